// Round 3
// baseline (1211.123 us; speedup 1.0000x reference)
//
#include <hip/hip_runtime.h>
#include <math.h>

#define NN 50000
#define NE 800000
#define GG 64
#define ATT_SCALE 0.25f   // 1/sqrt(16)
#define SCAN_BLK 512
#define SCAN_NB ((NN + SCAN_BLK - 1) / SCAN_BLK)   // 98
#define CSR_CAP (NE + 4 * NN)                      // padded CSR capacity

// ---------------- group sizes via binary search (batch is sorted) ----------------

__global__ void k_bounds(const int* __restrict__ batch, float* __restrict__ inv) {
    int g = threadIdx.x;
    if (g >= GG) return;
    int lo = 0, hi = NN;
    while (lo < hi) { int mid = (lo + hi) >> 1; if (batch[mid] < g) lo = mid + 1; else hi = mid; }
    int lb = lo;
    lo = 0; hi = NN;
    int g1 = g + 1;
    while (lo < hi) { int mid = (lo + hi) >> 1; if (batch[mid] < g1) lo = mid + 1; else hi = mid; }
    inv[g] = 1.0f / fmaxf((float)(lo - lb), 1.0f);
}

// ---------------- CSR build: deg -> 4-aligned exclusive scan -> fill ----------------

__global__ __launch_bounds__(256) void k_deg(const int* __restrict__ dstv,
                                             int* __restrict__ deg) {
    int e = blockIdx.x * 256 + threadIdx.x;
    if (e < NE) atomicAdd(&deg[dstv[e]], 1);
}

__global__ __launch_bounds__(SCAN_BLK) void k_scan1(const int* __restrict__ deg,
                                                    int* __restrict__ locoff,
                                                    int* __restrict__ bsum) {
    __shared__ int sh[SCAN_BLK];
    int tid = threadIdx.x;
    int n = blockIdx.x * SCAN_BLK + tid;
    int v = (n < NN) ? ((deg[n] + 3) & ~3) : 0;
    sh[tid] = v;
    __syncthreads();
    for (int off = 1; off < SCAN_BLK; off <<= 1) {
        int t = (tid >= off) ? sh[tid - off] : 0;
        __syncthreads();
        sh[tid] += t;
        __syncthreads();
    }
    if (n < NN) locoff[n] = sh[tid] - v;   // exclusive
    if (tid == SCAN_BLK - 1) bsum[blockIdx.x] = sh[tid];
}

__global__ void k_scan2(int* __restrict__ bsum) {
    __shared__ int sh[128];
    int t = threadIdx.x;
    int v = (t < SCAN_NB) ? bsum[t] : 0;
    sh[t] = v;
    __syncthreads();
    for (int off = 1; off < 128; off <<= 1) {
        int u = (t >= off) ? sh[t - off] : 0;
        __syncthreads();
        sh[t] += u;
        __syncthreads();
    }
    if (t < SCAN_NB) bsum[t] = sh[t] - v;  // exclusive
}

__global__ __launch_bounds__(256) void k_scan3(const int* __restrict__ locoff,
                                               const int* __restrict__ bsum,
                                               int* __restrict__ off) {
    int n = blockIdx.x * 256 + threadIdx.x;
    if (n < NN) off[n] = locoff[n] + bsum[n >> 9];
}

__global__ __launch_bounds__(256) void k_fill(const int* __restrict__ srcv,
                                              const int* __restrict__ dstv,
                                              const int* __restrict__ off,
                                              int* __restrict__ cursor,
                                              int* __restrict__ srcp,
                                              int* __restrict__ e2p) {
    int e = blockIdx.x * 256 + threadIdx.x;
    if (e < NE) {
        int d = dstv[e];
        int r = atomicAdd(&cursor[d], 1);
        int p = off[d] + r;
        srcp[p] = srcv[e];
        e2p[p] = e;
    }
}

// M[l][i][c] = sum_dd Wq[l][i][h*16+dd] * We[l][j][h*16+dd],  c = h*16+j
__global__ __launch_bounds__(256) void k_M(const float* __restrict__ Wq,
                                           const float* __restrict__ We,
                                           float* __restrict__ M) {
    int t = blockIdx.x * 256 + threadIdx.x;
    if (t >= 5 * 64 * 64) return;
    int l = t >> 12, i = (t >> 6) & 63, c = t & 63;
    int hh = c >> 4, j = c & 15;
    const float* wq = Wq + l * 4096 + i * 64 + hh * 16;
    const float* we = We + l * 1024 + j * 64 + hh * 16;
    float acc = 0.f;
#pragma unroll
    for (int dd = 0; dd < 16; ++dd) acc += wq[dd] * we[dd];
    M[t] = acc;
}

// ---------------- fused projections: Q,K,V,Skip (LDS b128) + QW (L1) ----------------
// block=256 (4 waves), 8 nodes/wave, 32 nodes/block; grid = 1563

__global__ __launch_bounds__(256) void k_proj(const float* __restrict__ hsrc,
                                              const float* __restrict__ Wq,
                                              const float* __restrict__ Wk,
                                              const float* __restrict__ Wv,
                                              const float* __restrict__ Wsk,
                                              const float* __restrict__ Mw,
                                              float* __restrict__ Q, float* __restrict__ K,
                                              float* __restrict__ V, float* __restrict__ S,
                                              float* __restrict__ QW) {
    __shared__ float wT[4096 * 4];   // [k*64+c][m], 64 KB, read as b128
    __shared__ float hT[32 * 64];    // 8 KB node tile
    int tid = threadIdx.x;
    for (int i = tid; i < 4096; i += 256) {
        float4 w = make_float4(Wq[i], Wk[i], Wv[i], Wsk[i]);
        *reinterpret_cast<float4*>(&wT[i * 4]) = w;
    }
    int nb0 = blockIdx.x * 32;
    for (int i = tid; i < 2048; i += 256) {
        int gi = nb0 * 64 + i;
        hT[i] = (gi < NN * 64) ? hsrc[gi] : 0.f;
    }
    __syncthreads();

    int lane = tid & 63, wv = tid >> 6;
    float acc[8][5];
#pragma unroll
    for (int i = 0; i < 8; ++i)
#pragma unroll
        for (int m = 0; m < 5; ++m) acc[i][m] = 0.f;

    int hbase = wv * 8 * 64;

    for (int k = 0; k < 64; k += 4) {
        float4 hreg[8];
#pragma unroll
        for (int i = 0; i < 8; ++i)
            hreg[i] = *reinterpret_cast<const float4*>(&hT[hbase + i * 64 + k]);
#pragma unroll
        for (int kk = 0; kk < 4; ++kk) {
            float4 w = *reinterpret_cast<const float4*>(&wT[((k + kk) * 64 + lane) * 4]);
            float wm = Mw[(k + kk) * 64 + lane];
#pragma unroll
            for (int i = 0; i < 8; ++i) {
                float hv = reinterpret_cast<const float*>(&hreg[i])[kk];
                acc[i][0] = fmaf(hv, w.x, acc[i][0]);
                acc[i][1] = fmaf(hv, w.y, acc[i][1]);
                acc[i][2] = fmaf(hv, w.z, acc[i][2]);
                acc[i][3] = fmaf(hv, w.w, acc[i][3]);
                acc[i][4] = fmaf(hv, wm,  acc[i][4]);
            }
        }
    }
#pragma unroll
    for (int i = 0; i < 8; ++i) {
        int node = nb0 + wv * 8 + i;
        if (node < NN) {
            int base = node * 64 + lane;
            Q[base]  = acc[i][0];
            K[base]  = acc[i][1];
            V[base]  = acc[i][2];
            S[base]  = acc[i][3];
            QW[base] = acc[i][4];
        }
    }
}

// ---------------- per-node online-softmax attention + relu + pool ----------------
// block=256 (4 waves), one node per wave; 4-edge batches, 2-stage pipeline

__global__ __launch_bounds__(256) void k_attn(const float* __restrict__ Q,
                                              const float* __restrict__ K,
                                              const float* __restrict__ V,
                                              const float* __restrict__ S,
                                              const float* __restrict__ QW,
                                              const float* __restrict__ Wel,
                                              const float* __restrict__ eattr,
                                              const int* __restrict__ srcp,
                                              const int* __restrict__ e2p,
                                              const int* __restrict__ offp,
                                              const int* __restrict__ cnt,
                                              const int* __restrict__ batch,
                                              const float* __restrict__ inv,
                                              float* __restrict__ Hout,
                                              float* __restrict__ hcat,
                                              int layer) {
    __shared__ float we[16 * 64];   // 4 KB
    int tid = threadIdx.x;
    for (int i = tid; i < 1024; i += 256) we[i] = Wel[i];
    __syncthreads();

    int lane = tid & 63;
    int n = blockIdx.x * 4 + (tid >> 6);
    if (n >= NN) return;

    int dd = lane & 15;     // attr/channel index within head
    int hg = lane >> 4;     // head (also: edge slot whose attr this lane carries)

    float q  = Q[n * 64 + lane];
    float qw = QW[n * 64 + lane];
    int dg   = cnt[n];
    int pos0 = offp[n];
    int nbt  = (dg + 3) >> 2;

    float m = -1e30f, s = 0.f, av = 0.f, aa = 0.f;

    auto ldidx = [&](int b, int4& sn, int4& ee) {
        if (b < nbt) {
            sn = *reinterpret_cast<const int4*>(srcp + pos0 + b * 4);
            ee = *reinterpret_cast<const int4*>(e2p + pos0 + b * 4);
        } else {
            sn = make_int4(0, 0, 0, 0);
            ee = make_int4(0, 0, 0, 0);
        }
    };
    auto issue = [&](const int4& sn, const int4& ee, float (&kk)[4], float (&vv)[4], float& at) {
        kk[0] = K[sn.x * 64 + lane];  vv[0] = V[sn.x * 64 + lane];
        kk[1] = K[sn.y * 64 + lane];  vv[1] = V[sn.y * 64 + lane];
        kk[2] = K[sn.z * 64 + lane];  vv[2] = V[sn.z * 64 + lane];
        kk[3] = K[sn.w * 64 + lane];  vv[3] = V[sn.w * 64 + lane];
        int ej = (hg == 0) ? ee.x : (hg == 1) ? ee.y : (hg == 2) ? ee.z : ee.w;
        at = eattr[ej * 16 + dd];     // lane l carries attr[edge l>>4][l&15]
    };
    auto compute = [&](int b, const float (&kk)[4], const float (&vv)[4], float at4) {
        int rem = dg - b * 4;
#pragma unroll
        for (int j = 0; j < 4; ++j) {
            float atj = __shfl(at4, (j << 4) | dd, 64);
            float p = fmaf(q, kk[j], qw * atj);
            p += __shfl_xor(p, 1, 16);
            p += __shfl_xor(p, 2, 16);
            p += __shfl_xor(p, 4, 16);
            p += __shfl_xor(p, 8, 16);
            float logit = (j < rem) ? p * ATT_SCALE : -1e30f;
            float mn = fmaxf(m, logit);
            float wold = __expf(m - mn);
            float a = __expf(logit - mn);
            s  = fmaf(s,  wold, a);
            av = fmaf(av, wold, a * vv[j]);
            aa = fmaf(aa, wold, a * atj);
            m = mn;
        }
    };

    int4 sn0, ee0, sn1, ee1;
    float kk0[4], vv0[4], at0, kk1[4], vv1[4], at1;

    ldidx(0, sn0, ee0);
    issue(sn0, ee0, kk0, vv0, at0);
    ldidx(1, sn1, ee1);

    int b = 0;
    while (b + 1 < nbt) {
        issue(sn1, ee1, kk1, vv1, at1);       // gathers for batch b+1
        ldidx(b + 2, sn0, ee0);               // indices for batch b+2
        compute(b, kk0, vv0, at0);
        if (b + 2 < nbt) {
            issue(sn0, ee0, kk0, vv0, at0);   // gathers for batch b+2
            ldidx(b + 3, sn1, ee1);           // indices for batch b+3
        }
        compute(b + 1, kk1, vv1, at1);
        b += 2;
    }
    if (b < nbt) compute(b, kk0, vv0, at0);

    float rden = 1.0f / (s + 1e-16f);
    float eagg = 0.f;
#pragma unroll
    for (int j = 0; j < 16; ++j) {
        float aj = __shfl(aa, hg * 16 + j, 64);
        eagg = fmaf(aj, we[j * 64 + lane], eagg);
    }
    float agg = (av + eagg) * rden;
    float hn = fmaxf(agg + S[n * 64 + lane], 0.f);
    Hout[n * 64 + lane] = hn;

    int g = batch[n];
    atomicAdd(&hcat[g * 320 + layer * 64 + lane], hn * inv[g]);
}

// ---------------- final MLP: one block per graph ----------------

__global__ __launch_bounds__(256) void k_mlp(const float* __restrict__ hcat,
                                             const float* __restrict__ W1,
                                             const float* __restrict__ b1,
                                             const float* __restrict__ W2,
                                             const float* __restrict__ b2,
                                             float* __restrict__ out) {
    __shared__ float hc[320];
    __shared__ float red[256];
    int g = blockIdx.x, tid = threadIdx.x;
    for (int i = tid; i < 320; i += 256) hc[i] = hcat[g * 320 + i];
    __syncthreads();
    float part = 0.f;
    for (int j = tid; j < 320; j += 256) {
        float t = b1[j];
        for (int k = 0; k < 320; ++k) t = fmaf(hc[k], W1[k * 320 + j], t);
        part = fmaf(fmaxf(t, 0.f), W2[j], part);
    }
    red[tid] = part;
    __syncthreads();
    for (int off = 128; off > 0; off >>= 1) {
        if (tid < off) red[tid] += red[tid + off];
        __syncthreads();
    }
    if (tid == 0) out[g] = red[0] + b2[0];
}

// ---------------- launch ----------------

extern "C" void kernel_launch(void* const* d_in, const int* in_sizes, int n_in,
                              void* d_out, int out_size, void* d_ws, size_t ws_size,
                              hipStream_t stream) {
    const float* x     = (const float*)d_in[0];
    const int*   ei    = (const int*)d_in[1];     // [2,E]: src then dst
    const float* eattr = (const float*)d_in[2];
    const int*   batch = (const int*)d_in[3];
    const float* Wq    = (const float*)d_in[4];
    const float* Wk    = (const float*)d_in[5];
    const float* Wv    = (const float*)d_in[6];
    const float* We    = (const float*)d_in[7];
    const float* Wsk   = (const float*)d_in[8];
    const float* W1    = (const float*)d_in[9];
    const float* b1    = (const float*)d_in[10];
    const float* W2    = (const float*)d_in[11];
    const float* b2    = (const float*)d_in[12];
    float* out = (float*)d_out;

    const int* srcv = ei;
    const int* dstv = ei + NE;

    // workspace carve (floats; every base is a multiple of 4 elements -> 16B aligned)
    float* ws = (float*)d_ws;
    size_t o = 0;
    float* Q    = ws + o; o += (size_t)NN * 64;
    float* K    = ws + o; o += (size_t)NN * 64;
    float* V    = ws + o; o += (size_t)NN * 64;
    float* S    = ws + o; o += (size_t)NN * 64;
    float* QW   = ws + o; o += (size_t)NN * 64;
    float* Hb   = ws + o; o += (size_t)NN * 64;
    float* Mw   = ws + o; o += 5 * 4096;
    float* inv  = ws + o; o += GG;
    // ---- zeroed region start ----
    float* hcat = ws + o; o += GG * 320;
    int*   deg  = (int*)(ws + o); o += NN;          // true degrees (cnt)
    int*   cursor = (int*)(ws + o); o += NN;
    int*   srcp = (int*)(ws + o); o += CSR_CAP;
    int*   e2p  = (int*)(ws + o); o += CSR_CAP;
    size_t zwords = (size_t)(GG * 320 + NN + NN) + 2 * (size_t)CSR_CAP;
    // ---- zeroed region end ----
    int*   off    = (int*)(ws + o); o += NN;
    int*   locoff = (int*)(ws + o); o += NN;
    int*   bsum   = (int*)(ws + o); o += 128;

    hipMemsetAsync(hcat, 0, zwords * 4, stream);

    k_bounds<<<1, 64, 0, stream>>>(batch, inv);
    k_deg<<<(NE + 255) / 256, 256, 0, stream>>>(dstv, deg);
    k_scan1<<<SCAN_NB, SCAN_BLK, 0, stream>>>(deg, locoff, bsum);
    k_scan2<<<1, 128, 0, stream>>>(bsum);
    k_scan3<<<(NN + 255) / 256, 256, 0, stream>>>(locoff, bsum, off);
    k_fill<<<(NE + 255) / 256, 256, 0, stream>>>(srcv, dstv, off, cursor, srcp, e2p);
    k_M<<<(5 * 4096 + 255) / 256, 256, 0, stream>>>(Wq, We, Mw);

    const float* hsrc = x;
    for (int l = 0; l < 5; ++l) {
        k_proj<<<(NN + 31) / 32, 256, 0, stream>>>(hsrc,
                                                   Wq + l * 4096, Wk + l * 4096,
                                                   Wv + l * 4096, Wsk + l * 4096,
                                                   Mw + l * 4096,
                                                   Q, K, V, S, QW);
        k_attn<<<(NN + 3) / 4, 256, 0, stream>>>(Q, K, V, S, QW,
                                                 We + l * 1024, eattr,
                                                 srcp, e2p, off, deg,
                                                 batch, inv, Hb, hcat, l);
        hsrc = Hb;
    }
    k_mlp<<<GG, 256, 0, stream>>>(hcat, W1, b1, W2, b2, out);
}

// Round 4
// 1016.217 us; speedup vs baseline: 1.1918x; 1.1918x over previous
//
#include <hip/hip_runtime.h>
#include <math.h>

#define NN 50000
#define NE 800000
#define GG 64
#define ATT_SCALE 0.25f   // 1/sqrt(16)
#define SCAN_BLK 512
#define SCAN_NB ((NN + SCAN_BLK - 1) / SCAN_BLK)   // 98
#define CSR_CAP (NE + 4 * NN)                      // 4-aligned-per-node CSR capacity

typedef unsigned int uint;
typedef unsigned short ushort;

__device__ __forceinline__ uint bf16r(float x) {   // RNE f32 -> bf16 bits
    uint u = __float_as_uint(x);
    return (u + 0x7fffu + ((u >> 16) & 1u)) >> 16;
}

// ---------------- group sizes via binary search (batch is sorted) ----------------

__global__ void k_bounds(const int* __restrict__ batch, float* __restrict__ inv) {
    int g = threadIdx.x;
    if (g >= GG) return;
    int lo = 0, hi = NN;
    while (lo < hi) { int mid = (lo + hi) >> 1; if (batch[mid] < g) lo = mid + 1; else hi = mid; }
    int lb = lo;
    lo = 0; hi = NN;
    int g1 = g + 1;
    while (lo < hi) { int mid = (lo + hi) >> 1; if (batch[mid] < g1) lo = mid + 1; else hi = mid; }
    inv[g] = 1.0f / fmaxf((float)(lo - lb), 1.0f);
}

// ---------------- CSR build ----------------

__global__ __launch_bounds__(256) void k_degrank(const int* __restrict__ dstv,
                                                 int* __restrict__ deg,
                                                 int* __restrict__ rank) {
    int e = blockIdx.x * 256 + threadIdx.x;
    if (e < NE) rank[e] = atomicAdd(&deg[dstv[e]], 1);
}

__global__ __launch_bounds__(SCAN_BLK) void k_scan1(const int* __restrict__ deg,
                                                    int* __restrict__ locoff,
                                                    int* __restrict__ bsum) {
    __shared__ int sh[SCAN_BLK];
    int tid = threadIdx.x;
    int n = blockIdx.x * SCAN_BLK + tid;
    int v = (n < NN) ? ((deg[n] + 3) & ~3) : 0;
    sh[tid] = v;
    __syncthreads();
    for (int off = 1; off < SCAN_BLK; off <<= 1) {
        int t = (tid >= off) ? sh[tid - off] : 0;
        __syncthreads();
        sh[tid] += t;
        __syncthreads();
    }
    if (n < NN) locoff[n] = sh[tid] - v;   // exclusive
    if (tid == SCAN_BLK - 1) bsum[blockIdx.x] = sh[tid];
}

__global__ void k_scan2(int* __restrict__ bsum) {
    __shared__ int sh[128];
    int t = threadIdx.x;
    int v = (t < SCAN_NB) ? bsum[t] : 0;
    sh[t] = v;
    __syncthreads();
    for (int off = 1; off < 128; off <<= 1) {
        int u = (t >= off) ? sh[t - off] : 0;
        __syncthreads();
        sh[t] += u;
        __syncthreads();
    }
    if (t < SCAN_NB) bsum[t] = sh[t] - v;  // exclusive
}

__global__ __launch_bounds__(256) void k_scan3(const int* __restrict__ locoff,
                                               const int* __restrict__ bsum,
                                               int* __restrict__ off) {
    int n = blockIdx.x * 256 + threadIdx.x;
    if (n < NN) off[n] = locoff[n] + bsum[n >> 9];
}

// fill srcp + CSR-ordered bf16 attrs (no atomics: rank precomputed)
__global__ __launch_bounds__(256) void k_fill(const int* __restrict__ srcv,
                                              const int* __restrict__ dstv,
                                              const float* __restrict__ eattr,
                                              const int* __restrict__ off,
                                              const int* __restrict__ rank,
                                              int* __restrict__ srcp,
                                              ushort* __restrict__ aperm) {
    int e = blockIdx.x * 256 + threadIdx.x;
    if (e >= NE) return;
    int d = dstv[e];
    int p = off[d] + rank[e];
    srcp[p] = srcv[e];
    const float4* ea = reinterpret_cast<const float4*>(eattr + (size_t)e * 16);
    float4 a = ea[0], b = ea[1], c = ea[2], d4 = ea[3];
    uint4 u0, u1;
    u0.x = bf16r(a.x) | (bf16r(a.y) << 16);
    u0.y = bf16r(a.z) | (bf16r(a.w) << 16);
    u0.z = bf16r(b.x) | (bf16r(b.y) << 16);
    u0.w = bf16r(b.z) | (bf16r(b.w) << 16);
    u1.x = bf16r(c.x) | (bf16r(c.y) << 16);
    u1.y = bf16r(c.z) | (bf16r(c.w) << 16);
    u1.z = bf16r(d4.x) | (bf16r(d4.y) << 16);
    u1.w = bf16r(d4.z) | (bf16r(d4.w) << 16);
    uint4* ap = reinterpret_cast<uint4*>(aperm + (size_t)p * 16);
    ap[0] = u0;
    ap[1] = u1;
}

// M[l][i][c] = sum_dd Wq[l][i][h*16+dd] * We[l][j][h*16+dd],  c = h*16+j
__global__ __launch_bounds__(256) void k_M(const float* __restrict__ Wq,
                                           const float* __restrict__ We,
                                           float* __restrict__ M) {
    int t = blockIdx.x * 256 + threadIdx.x;
    if (t >= 5 * 64 * 64) return;
    int l = t >> 12, i = (t >> 6) & 63, c = t & 63;
    int hh = c >> 4, j = c & 15;
    const float* wq = Wq + l * 4096 + i * 64 + hh * 16;
    const float* we = We + l * 1024 + j * 64 + hh * 16;
    float acc = 0.f;
#pragma unroll
    for (int dd = 0; dd < 16; ++dd) acc += wq[dd] * we[dd];
    M[t] = acc;
}

// ---------------- fused projections: Q,S,QW f32 + packed bf16 KV ----------------
// block=256 (4 waves), 8 nodes/wave, 32 nodes/block; grid = 1563

__global__ __launch_bounds__(256) void k_proj(const float* __restrict__ hsrc,
                                              const float* __restrict__ Wq,
                                              const float* __restrict__ Wk,
                                              const float* __restrict__ Wv,
                                              const float* __restrict__ Wsk,
                                              const float* __restrict__ Mw,
                                              float* __restrict__ Q,
                                              uint* __restrict__ KVp,
                                              float* __restrict__ S,
                                              float* __restrict__ QW) {
    __shared__ float wT[4096 * 4];   // [k*64+c][{q,k,v,sk}], 64 KB, read as b128
    __shared__ float hT[32 * 64];    // 8 KB node tile
    int tid = threadIdx.x;
    for (int i4 = tid * 4; i4 < 4096; i4 += 1024) {
        float4 a = *reinterpret_cast<const float4*>(Wq + i4);
        float4 b = *reinterpret_cast<const float4*>(Wk + i4);
        float4 c = *reinterpret_cast<const float4*>(Wv + i4);
        float4 d = *reinterpret_cast<const float4*>(Wsk + i4);
        *reinterpret_cast<float4*>(&wT[(i4 + 0) * 4]) = make_float4(a.x, b.x, c.x, d.x);
        *reinterpret_cast<float4*>(&wT[(i4 + 1) * 4]) = make_float4(a.y, b.y, c.y, d.y);
        *reinterpret_cast<float4*>(&wT[(i4 + 2) * 4]) = make_float4(a.z, b.z, c.z, d.z);
        *reinterpret_cast<float4*>(&wT[(i4 + 3) * 4]) = make_float4(a.w, b.w, c.w, d.w);
    }
    int nb0 = blockIdx.x * 32;
    for (int i4 = tid * 4; i4 < 2048; i4 += 1024) {
        size_t gi = (size_t)nb0 * 64 + i4;
        if (gi + 3 < (size_t)NN * 64) {
            *reinterpret_cast<float4*>(&hT[i4]) = *reinterpret_cast<const float4*>(hsrc + gi);
        } else {
#pragma unroll
            for (int j = 0; j < 4; ++j)
                hT[i4 + j] = (gi + j < (size_t)NN * 64) ? hsrc[gi + j] : 0.f;
        }
    }
    __syncthreads();

    int lane = tid & 63, wv = tid >> 6;
    float acc[8][5];
#pragma unroll
    for (int i = 0; i < 8; ++i)
#pragma unroll
        for (int m = 0; m < 5; ++m) acc[i][m] = 0.f;

    int hbase = wv * 8 * 64;

    for (int k = 0; k < 64; k += 4) {
        float4 hreg[8];
#pragma unroll
        for (int i = 0; i < 8; ++i)
            hreg[i] = *reinterpret_cast<const float4*>(&hT[hbase + i * 64 + k]);
#pragma unroll
        for (int kk = 0; kk < 4; ++kk) {
            float4 w = *reinterpret_cast<const float4*>(&wT[((k + kk) * 64 + lane) * 4]);
            float wm = Mw[(k + kk) * 64 + lane];
#pragma unroll
            for (int i = 0; i < 8; ++i) {
                float hv = reinterpret_cast<const float*>(&hreg[i])[kk];
                acc[i][0] = fmaf(hv, w.x, acc[i][0]);
                acc[i][1] = fmaf(hv, w.y, acc[i][1]);
                acc[i][2] = fmaf(hv, w.z, acc[i][2]);
                acc[i][3] = fmaf(hv, w.w, acc[i][3]);
                acc[i][4] = fmaf(hv, wm,  acc[i][4]);
            }
        }
    }
#pragma unroll
    for (int i = 0; i < 8; ++i) {
        int node = nb0 + wv * 8 + i;
        if (node < NN) {
            int base = node * 64 + lane;
            Q[base]   = acc[i][0];
            KVp[base] = (bf16r(acc[i][1]) << 16) | bf16r(acc[i][2]);  // K hi, V lo
            S[base]   = acc[i][3];
            QW[base]  = acc[i][4];
        }
    }
}

// ---------------- per-node online-softmax attention + relu + pool ----------------
// block=256 (4 waves), one node per wave; 4-edge batches, 2-stage pipeline

__global__ __launch_bounds__(256) void k_attn(const float* __restrict__ Q,
                                              const uint* __restrict__ KVp,
                                              const float* __restrict__ S,
                                              const float* __restrict__ QW,
                                              const float* __restrict__ Wel,
                                              const ushort* __restrict__ aperm,
                                              const int* __restrict__ srcp,
                                              const int* __restrict__ offp,
                                              const int* __restrict__ cnt,
                                              const int* __restrict__ batch,
                                              const float* __restrict__ inv,
                                              float* __restrict__ Hout,
                                              float* __restrict__ hcat,
                                              int layer) {
    __shared__ float we[16 * 64];   // 4 KB
    int tid = threadIdx.x;
    for (int i = tid; i < 1024; i += 256) we[i] = Wel[i];
    __syncthreads();

    int lane = tid & 63;
    int n = blockIdx.x * 4 + (tid >> 6);
    if (n >= NN) return;

    int dd = lane & 15;     // channel within head
    int hg = lane >> 4;     // head (also: edge slot whose attr this lane carries)

    float q  = Q[n * 64 + lane];
    float qw = QW[n * 64 + lane];
    int dg   = cnt[n];
    int pos0 = offp[n];
    int nbt  = (dg + 3) >> 2;

    float m = -1e30f, s = 0.f, av = 0.f, aa = 0.f;

    auto ldidx = [&](int b, int4& sn) {
        sn = (b < nbt) ? *reinterpret_cast<const int4*>(srcp + pos0 + b * 4)
                       : make_int4(0, 0, 0, 0);
    };
    auto issue = [&](int b, const int4& sn, uint (&kv)[4], float& at) {
        kv[0] = KVp[sn.x * 64 + lane];
        kv[1] = KVp[sn.y * 64 + lane];
        kv[2] = KVp[sn.z * 64 + lane];
        kv[3] = KVp[sn.w * 64 + lane];
        at = __uint_as_float((uint)aperm[(size_t)(pos0 + b * 4) * 16 + lane] << 16);
    };
    auto compute = [&](int b, const uint (&kv)[4], float at4) {
        int rem = dg - b * 4;
#pragma unroll
        for (int j = 0; j < 4; ++j) {
            uint w = kv[j];
            float kf = __uint_as_float(w & 0xffff0000u);
            float vf = __uint_as_float(w << 16);
            float atj = __shfl(at4, (j << 4) | dd, 64);
            float p = fmaf(q, kf, qw * atj);
            p += __shfl_xor(p, 1, 16);
            p += __shfl_xor(p, 2, 16);
            p += __shfl_xor(p, 4, 16);
            p += __shfl_xor(p, 8, 16);
            float logit = (j < rem) ? p * ATT_SCALE : -1e30f;
            float mn = fmaxf(m, logit);
            float wold = __expf(m - mn);
            float a = __expf(logit - mn);
            s  = fmaf(s,  wold, a);
            av = fmaf(av, wold, a * vf);
            aa = fmaf(aa, wold, a * atj);
            m = mn;
        }
    };

    int4 sn0, sn1;
    uint kv0[4], kv1[4];
    float at0, at1;

    ldidx(0, sn0);
    issue(0, sn0, kv0, at0);
    ldidx(1, sn1);

    int b = 0;
    while (b + 1 < nbt) {
        issue(b + 1, sn1, kv1, at1);          // gathers for batch b+1
        ldidx(b + 2, sn0);                    // indices for batch b+2
        compute(b, kv0, at0);
        if (b + 2 < nbt) {
            issue(b + 2, sn0, kv0, at0);      // gathers for batch b+2
            ldidx(b + 3, sn1);                // indices for batch b+3
        }
        compute(b + 1, kv1, at1);
        b += 2;
    }
    if (b < nbt) compute(b, kv0, at0);

    float rden = 1.0f / (s + 1e-16f);
    float eagg = 0.f;
#pragma unroll
    for (int j = 0; j < 16; ++j) {
        float aj = __shfl(aa, hg * 16 + j, 64);
        eagg = fmaf(aj, we[j * 64 + lane], eagg);
    }
    float agg = (av + eagg) * rden;
    float hn = fmaxf(agg + S[n * 64 + lane], 0.f);
    Hout[n * 64 + lane] = hn;

    int g = batch[n];
    atomicAdd(&hcat[g * 320 + layer * 64 + lane], hn * inv[g]);
}

// ---------------- final MLP: one block per graph ----------------

__global__ __launch_bounds__(256) void k_mlp(const float* __restrict__ hcat,
                                             const float* __restrict__ W1,
                                             const float* __restrict__ b1,
                                             const float* __restrict__ W2,
                                             const float* __restrict__ b2,
                                             float* __restrict__ out) {
    __shared__ float hc[320];
    __shared__ float red[256];
    int g = blockIdx.x, tid = threadIdx.x;
    for (int i = tid; i < 320; i += 256) hc[i] = hcat[g * 320 + i];
    __syncthreads();
    float part = 0.f;
    for (int j = tid; j < 320; j += 256) {
        float t = b1[j];
        for (int k = 0; k < 320; ++k) t = fmaf(hc[k], W1[k * 320 + j], t);
        part = fmaf(fmaxf(t, 0.f), W2[j], part);
    }
    red[tid] = part;
    __syncthreads();
    for (int off = 128; off > 0; off >>= 1) {
        if (tid < off) red[tid] += red[tid + off];
        __syncthreads();
    }
    if (tid == 0) out[g] = red[0] + b2[0];
}

// ---------------- launch ----------------

extern "C" void kernel_launch(void* const* d_in, const int* in_sizes, int n_in,
                              void* d_out, int out_size, void* d_ws, size_t ws_size,
                              hipStream_t stream) {
    const float* x     = (const float*)d_in[0];
    const int*   ei    = (const int*)d_in[1];     // [2,E]: src then dst
    const float* eattr = (const float*)d_in[2];
    const int*   batch = (const int*)d_in[3];
    const float* Wq    = (const float*)d_in[4];
    const float* Wk    = (const float*)d_in[5];
    const float* Wv    = (const float*)d_in[6];
    const float* We    = (const float*)d_in[7];
    const float* Wsk   = (const float*)d_in[8];
    const float* W1    = (const float*)d_in[9];
    const float* b1    = (const float*)d_in[10];
    const float* W2    = (const float*)d_in[11];
    const float* b2    = (const float*)d_in[12];
    float* out = (float*)d_out;

    const int* srcv = ei;
    const int* dstv = ei + NE;

    // workspace carve (float words; all bases 16B-aligned)
    float* ws = (float*)d_ws;
    size_t o = 0;
    float* Q    = ws + o; o += (size_t)NN * 64;
    uint*  KVp  = (uint*)(ws + o); o += (size_t)NN * 64;
    float* S    = ws + o; o += (size_t)NN * 64;
    float* QW   = ws + o; o += (size_t)NN * 64;
    float* Hb   = ws + o; o += (size_t)NN * 64;
    float* Mw   = ws + o; o += 5 * 4096;
    float* inv  = ws + o; o += GG;
    // ---- zeroed region start ----
    float* hcat = ws + o; o += GG * 320;
    int*   deg  = (int*)(ws + o); o += NN;
    int*   srcp = (int*)(ws + o); o += CSR_CAP;    // pad slots must be 0 (safe gathers)
    size_t zwords = (size_t)GG * 320 + NN + CSR_CAP;
    // ---- zeroed region end ----
    int*    rank   = (int*)(ws + o); o += NE;
    int*    off    = (int*)(ws + o); o += NN;
    int*    locoff = (int*)(ws + o); o += NN;
    int*    bsum   = (int*)(ws + o); o += 128;
    ushort* aperm  = (ushort*)(ws + o); o += (size_t)CSR_CAP * 8;  // 16 ushorts/slot

    hipMemsetAsync(hcat, 0, zwords * 4, stream);

    k_bounds<<<1, 64, 0, stream>>>(batch, inv);
    k_degrank<<<(NE + 255) / 256, 256, 0, stream>>>(dstv, deg, rank);
    k_scan1<<<SCAN_NB, SCAN_BLK, 0, stream>>>(deg, locoff, bsum);
    k_scan2<<<1, 128, 0, stream>>>(bsum);
    k_scan3<<<(NN + 255) / 256, 256, 0, stream>>>(locoff, bsum, off);
    k_fill<<<(NE + 255) / 256, 256, 0, stream>>>(srcv, dstv, eattr, off, rank, srcp, aperm);
    k_M<<<(5 * 4096 + 255) / 256, 256, 0, stream>>>(Wq, We, Mw);

    const float* hsrc = x;
    for (int l = 0; l < 5; ++l) {
        k_proj<<<(NN + 31) / 32, 256, 0, stream>>>(hsrc,
                                                   Wq + l * 4096, Wk + l * 4096,
                                                   Wv + l * 4096, Wsk + l * 4096,
                                                   Mw + l * 4096,
                                                   Q, KVp, S, QW);
        k_attn<<<(NN + 3) / 4, 256, 0, stream>>>(Q, KVp, S, QW,
                                                 We + l * 1024, aperm,
                                                 srcp, off, deg,
                                                 batch, inv, Hb, hcat, l);
        hsrc = Hb;
    }
    k_mlp<<<GG, 256, 0, stream>>>(hcat, W1, b1, W2, b2, out);
}

// Round 5
// 814.059 us; speedup vs baseline: 1.4878x; 1.2483x over previous
//
#include <hip/hip_runtime.h>
#include <math.h>

#define NN 50000
#define NE 800000
#define GG 64
#define ATT_SCALE 0.25f   // 1/sqrt(16)
#define SCAN_BLK 512
#define SCAN_NB ((NN + SCAN_BLK - 1) / SCAN_BLK)   // 98
#define CSR_CAP (NE + 4 * NN)                      // 4-aligned-per-node CSR capacity

typedef unsigned int uint;
typedef unsigned short ushort;

__device__ __forceinline__ uint bf16r(float x) {   // RNE f32 -> bf16 bits
    uint u = __float_as_uint(x);
    return (u + 0x7fffu + ((u >> 16) & 1u)) >> 16;
}

// ---------------- graph segment bounds (batch is sorted) ----------------

__global__ void k_bounds(const int* __restrict__ batch, int* __restrict__ bstart,
                         float* __restrict__ inv) {
    __shared__ int sb[65];
    int t = threadIdx.x;
    if (t <= 64) {
        int lo = 0, hi = NN;
        while (lo < hi) { int mid = (lo + hi) >> 1; if (batch[mid] < t) lo = mid + 1; else hi = mid; }
        sb[t] = lo;
        bstart[t] = lo;
    }
    __syncthreads();
    if (t < 64) inv[t] = 1.0f / fmaxf((float)(sb[t + 1] - sb[t]), 1.0f);
}

// ---------------- CSR build ----------------

__global__ __launch_bounds__(256) void k_degrank(const int* __restrict__ dstv,
                                                 int* __restrict__ deg,
                                                 int* __restrict__ rank) {
    int e = blockIdx.x * 256 + threadIdx.x;
    if (e < NE) rank[e] = atomicAdd(&deg[dstv[e]], 1);
}

__global__ __launch_bounds__(SCAN_BLK) void k_scan1(const int* __restrict__ deg,
                                                    int* __restrict__ locoff,
                                                    int* __restrict__ bsum) {
    __shared__ int sh[SCAN_BLK];
    int tid = threadIdx.x;
    int n = blockIdx.x * SCAN_BLK + tid;
    int v = (n < NN) ? ((deg[n] + 3) & ~3) : 0;
    sh[tid] = v;
    __syncthreads();
    for (int off = 1; off < SCAN_BLK; off <<= 1) {
        int t = (tid >= off) ? sh[tid - off] : 0;
        __syncthreads();
        sh[tid] += t;
        __syncthreads();
    }
    if (n < NN) locoff[n] = sh[tid] - v;   // exclusive
    if (tid == SCAN_BLK - 1) bsum[blockIdx.x] = sh[tid];
}

__global__ void k_scan2(int* __restrict__ bsum) {
    __shared__ int sh[128];
    int t = threadIdx.x;
    int v = (t < SCAN_NB) ? bsum[t] : 0;
    sh[t] = v;
    __syncthreads();
    for (int off = 1; off < 128; off <<= 1) {
        int u = (t >= off) ? sh[t - off] : 0;
        __syncthreads();
        sh[t] += u;
        __syncthreads();
    }
    if (t < SCAN_NB) bsum[t] = sh[t] - v;  // exclusive
}

__global__ __launch_bounds__(256) void k_scan3(const int* __restrict__ locoff,
                                               const int* __restrict__ bsum,
                                               int* __restrict__ off) {
    int n = blockIdx.x * 256 + threadIdx.x;
    if (n < NN) off[n] = locoff[n] + bsum[n >> 9];
}

// fill srcp + CSR-ordered bf16 attrs (no atomics: rank precomputed)
__global__ __launch_bounds__(256) void k_fill(const int* __restrict__ srcv,
                                              const int* __restrict__ dstv,
                                              const float* __restrict__ eattr,
                                              const int* __restrict__ off,
                                              const int* __restrict__ rank,
                                              int* __restrict__ srcp,
                                              ushort* __restrict__ aperm) {
    int e = blockIdx.x * 256 + threadIdx.x;
    if (e >= NE) return;
    int d = dstv[e];
    int p = off[d] + rank[e];
    srcp[p] = srcv[e];
    const float4* ea = reinterpret_cast<const float4*>(eattr + (size_t)e * 16);
    float4 a = ea[0], b = ea[1], c = ea[2], d4 = ea[3];
    uint4 u0, u1;
    u0.x = bf16r(a.x) | (bf16r(a.y) << 16);
    u0.y = bf16r(a.z) | (bf16r(a.w) << 16);
    u0.z = bf16r(b.x) | (bf16r(b.y) << 16);
    u0.w = bf16r(b.z) | (bf16r(b.w) << 16);
    u1.x = bf16r(c.x) | (bf16r(c.y) << 16);
    u1.y = bf16r(c.z) | (bf16r(c.w) << 16);
    u1.z = bf16r(d4.x) | (bf16r(d4.y) << 16);
    u1.w = bf16r(d4.z) | (bf16r(d4.w) << 16);
    uint4* ap = reinterpret_cast<uint4*>(aperm + (size_t)p * 16);
    ap[0] = u0;
    ap[1] = u1;
}

// M[l][i][c] = sum_dd Wq[l][i][h*16+dd] * We[l][j][h*16+dd],  c = h*16+j
__global__ __launch_bounds__(256) void k_M(const float* __restrict__ Wq,
                                           const float* __restrict__ We,
                                           float* __restrict__ M) {
    int t = blockIdx.x * 256 + threadIdx.x;
    if (t >= 5 * 64 * 64) return;
    int l = t >> 12, i = (t >> 6) & 63, c = t & 63;
    int hh = c >> 4, j = c & 15;
    const float* wq = Wq + l * 4096 + i * 64 + hh * 16;
    const float* we = We + l * 1024 + j * 64 + hh * 16;
    float acc = 0.f;
#pragma unroll
    for (int dd = 0; dd < 16; ++dd) acc += wq[dd] * we[dd];
    M[t] = acc;
}

// ---------------- fused projections: Q,S,QW f32 + packed bf16 KV ----------------
// block=256 (4 waves), 8 nodes/wave, 32 nodes/block; grid = 1563

__global__ __launch_bounds__(256) void k_proj(const float* __restrict__ hsrc,
                                              const float* __restrict__ Wq,
                                              const float* __restrict__ Wk,
                                              const float* __restrict__ Wv,
                                              const float* __restrict__ Wsk,
                                              const float* __restrict__ Mw,
                                              float* __restrict__ Q,
                                              uint* __restrict__ KVp,
                                              float* __restrict__ S,
                                              float* __restrict__ QW) {
    __shared__ float wT[4096 * 4];   // [k*64+c][{q,k,v,sk}], 64 KB, read as b128
    __shared__ float hT[32 * 64];    // 8 KB node tile
    int tid = threadIdx.x;
    for (int i4 = tid * 4; i4 < 4096; i4 += 1024) {
        float4 a = *reinterpret_cast<const float4*>(Wq + i4);
        float4 b = *reinterpret_cast<const float4*>(Wk + i4);
        float4 c = *reinterpret_cast<const float4*>(Wv + i4);
        float4 d = *reinterpret_cast<const float4*>(Wsk + i4);
        *reinterpret_cast<float4*>(&wT[(i4 + 0) * 4]) = make_float4(a.x, b.x, c.x, d.x);
        *reinterpret_cast<float4*>(&wT[(i4 + 1) * 4]) = make_float4(a.y, b.y, c.y, d.y);
        *reinterpret_cast<float4*>(&wT[(i4 + 2) * 4]) = make_float4(a.z, b.z, c.z, d.z);
        *reinterpret_cast<float4*>(&wT[(i4 + 3) * 4]) = make_float4(a.w, b.w, c.w, d.w);
    }
    int nb0 = blockIdx.x * 32;
    for (int i4 = tid * 4; i4 < 2048; i4 += 1024) {
        size_t gi = (size_t)nb0 * 64 + i4;
        if (gi + 3 < (size_t)NN * 64) {
            *reinterpret_cast<float4*>(&hT[i4]) = *reinterpret_cast<const float4*>(hsrc + gi);
        } else {
#pragma unroll
            for (int j = 0; j < 4; ++j)
                hT[i4 + j] = (gi + j < (size_t)NN * 64) ? hsrc[gi + j] : 0.f;
        }
    }
    __syncthreads();

    int lane = tid & 63, wv = tid >> 6;
    float acc[8][5];
#pragma unroll
    for (int i = 0; i < 8; ++i)
#pragma unroll
        for (int m = 0; m < 5; ++m) acc[i][m] = 0.f;

    int hbase = wv * 8 * 64;

    for (int k = 0; k < 64; k += 4) {
        float4 hreg[8];
#pragma unroll
        for (int i = 0; i < 8; ++i)
            hreg[i] = *reinterpret_cast<const float4*>(&hT[hbase + i * 64 + k]);
#pragma unroll
        for (int kk = 0; kk < 4; ++kk) {
            float4 w = *reinterpret_cast<const float4*>(&wT[((k + kk) * 64 + lane) * 4]);
            float wm = Mw[(k + kk) * 64 + lane];
#pragma unroll
            for (int i = 0; i < 8; ++i) {
                float hv = reinterpret_cast<const float*>(&hreg[i])[kk];
                acc[i][0] = fmaf(hv, w.x, acc[i][0]);
                acc[i][1] = fmaf(hv, w.y, acc[i][1]);
                acc[i][2] = fmaf(hv, w.z, acc[i][2]);
                acc[i][3] = fmaf(hv, w.w, acc[i][3]);
                acc[i][4] = fmaf(hv, wm,  acc[i][4]);
            }
        }
    }
#pragma unroll
    for (int i = 0; i < 8; ++i) {
        int node = nb0 + wv * 8 + i;
        if (node < NN) {
            int base = node * 64 + lane;
            Q[base]   = acc[i][0];
            KVp[base] = (bf16r(acc[i][1]) << 16) | bf16r(acc[i][2]);  // K hi, V lo
            S[base]   = acc[i][3];
            QW[base]  = acc[i][4];
        }
    }
}

// ---------------- per-node online-softmax attention + relu (NO atomics) ----------------
// block=256 (4 waves), one node per wave; 4-edge batches, 2-stage pipeline,
// batch-max softmax (single rescale per 4 edges, ILP-4 butterflies)

__global__ __launch_bounds__(256) void k_attn(const float* __restrict__ Q,
                                              const uint* __restrict__ KVp,
                                              const float* __restrict__ S,
                                              const float* __restrict__ QW,
                                              const float* __restrict__ Wel,
                                              const ushort* __restrict__ aperm,
                                              const int* __restrict__ srcp,
                                              const int* __restrict__ offp,
                                              const int* __restrict__ cnt,
                                              float* __restrict__ Hout) {
    __shared__ float we[16 * 64];   // 4 KB
    int tid = threadIdx.x;
    for (int i = tid; i < 1024; i += 256) we[i] = Wel[i];
    __syncthreads();

    int lane = tid & 63;
    int n = blockIdx.x * 4 + (tid >> 6);
    if (n >= NN) return;

    int dd = lane & 15;     // channel within head
    int hg = lane >> 4;     // head (also: edge slot whose attr this lane carries)

    float q  = Q[n * 64 + lane];
    float qw = QW[n * 64 + lane];
    int dg   = cnt[n];
    int pos0 = offp[n];
    int nbt  = (dg + 3) >> 2;

    float m = -1e30f, s = 0.f, av = 0.f, aa = 0.f;

    auto ldidx = [&](int b, int4& sn) {
        sn = (b < nbt) ? *reinterpret_cast<const int4*>(srcp + pos0 + b * 4)
                       : make_int4(0, 0, 0, 0);
    };
    auto issue = [&](int b, const int4& sn, uint (&kv)[4], float& at) {
        kv[0] = KVp[sn.x * 64 + lane];
        kv[1] = KVp[sn.y * 64 + lane];
        kv[2] = KVp[sn.z * 64 + lane];
        kv[3] = KVp[sn.w * 64 + lane];
        at = __uint_as_float((uint)aperm[(size_t)(pos0 + b * 4) * 16 + lane] << 16);
    };
    auto compute = [&](int b, const uint (&kv)[4], float at4) {
        int rem = dg - b * 4;
        float l[4], atv[4], vf[4];
        // 4 independent butterfly chains (ILP-4), no softmax interleaved
#pragma unroll
        for (int j = 0; j < 4; ++j) {
            uint w = kv[j];
            float kf = __uint_as_float(w & 0xffff0000u);
            vf[j] = __uint_as_float(w << 16);
            float atj = __shfl(at4, (j << 4) | dd, 64);
            atv[j] = atj;
            float p = fmaf(q, kf, qw * atj);
            p += __shfl_xor(p, 1, 16);
            p += __shfl_xor(p, 2, 16);
            p += __shfl_xor(p, 4, 16);
            p += __shfl_xor(p, 8, 16);
            l[j] = (j < rem) ? p * ATT_SCALE : -1e30f;
        }
        // batch-max online softmax: ONE rescale per 4 edges (exact)
        float bm = fmaxf(fmaxf(l[0], l[1]), fmaxf(l[2], l[3]));
        float mn = fmaxf(m, bm);
        float wold = __expf(m - mn);
        float a0 = __expf(l[0] - mn);
        float a1 = __expf(l[1] - mn);
        float a2 = __expf(l[2] - mn);
        float a3 = __expf(l[3] - mn);
        s  = fmaf(s,  wold, (a0 + a1) + (a2 + a3));
        av = fmaf(av, wold, fmaf(a0, vf[0], fmaf(a1, vf[1], fmaf(a2, vf[2], a3 * vf[3]))));
        aa = fmaf(aa, wold, fmaf(a0, atv[0], fmaf(a1, atv[1], fmaf(a2, atv[2], a3 * atv[3]))));
        m = mn;
    };

    int4 sn0, sn1;
    uint kv0[4], kv1[4];
    float at0, at1;

    ldidx(0, sn0);
    issue(0, sn0, kv0, at0);
    ldidx(1, sn1);

    int b = 0;
    while (b + 1 < nbt) {
        issue(b + 1, sn1, kv1, at1);          // gathers for batch b+1
        ldidx(b + 2, sn0);                    // indices for batch b+2
        compute(b, kv0, at0);
        if (b + 2 < nbt) {
            issue(b + 2, sn0, kv0, at0);      // gathers for batch b+2
            ldidx(b + 3, sn1);                // indices for batch b+3
        }
        compute(b + 1, kv1, at1);
        b += 2;
    }
    if (b < nbt) compute(b, kv0, at0);

    float rden = 1.0f / (s + 1e-16f);
    float eagg = 0.f;
#pragma unroll
    for (int j = 0; j < 16; ++j) {
        float aj = __shfl(aa, hg * 16 + j, 64);
        eagg = fmaf(aj, we[j * 64 + lane], eagg);
    }
    float agg = (av + eagg) * rden;
    Hout[n * 64 + lane] = fmaxf(agg + S[n * 64 + lane], 0.f);
}

// ---------------- mean pool one layer: 64 blocks (one per graph), contiguous rows ----------------

__global__ __launch_bounds__(512) void k_pool(const float* __restrict__ H,
                                              const int* __restrict__ bstart,
                                              const float* __restrict__ inv,
                                              float* __restrict__ hcat,
                                              int layer) {
    __shared__ float red[512];
    int g = blockIdx.x;
    int lo = bstart[g], hi = bstart[g + 1];
    int ch = threadIdx.x & 63, ro = threadIdx.x >> 6;   // 8 row stripes
    float acc = 0.f;
    for (int r = lo + ro; r < hi; r += 8) acc += H[(size_t)r * 64 + ch];
    red[threadIdx.x] = acc;
    __syncthreads();
    if (ro < 4) red[threadIdx.x] += red[threadIdx.x + 256];
    __syncthreads();
    if (ro < 2) red[threadIdx.x] += red[threadIdx.x + 128];
    __syncthreads();
    if (ro == 0)
        hcat[g * 320 + layer * 64 + ch] = (red[ch] + red[64 + ch]) * inv[g];
}

// ---------------- final MLP: one block per graph ----------------

__global__ __launch_bounds__(256) void k_mlp(const float* __restrict__ hcat,
                                             const float* __restrict__ W1,
                                             const float* __restrict__ b1,
                                             const float* __restrict__ W2,
                                             const float* __restrict__ b2,
                                             float* __restrict__ out) {
    __shared__ float hc[320];
    __shared__ float red[256];
    int g = blockIdx.x, tid = threadIdx.x;
    for (int i = tid; i < 320; i += 256) hc[i] = hcat[g * 320 + i];
    __syncthreads();
    float part = 0.f;
    for (int j = tid; j < 320; j += 256) {
        float t = b1[j];
        for (int k = 0; k < 320; ++k) t = fmaf(hc[k], W1[k * 320 + j], t);
        part = fmaf(fmaxf(t, 0.f), W2[j], part);
    }
    red[tid] = part;
    __syncthreads();
    for (int off = 128; off > 0; off >>= 1) {
        if (tid < off) red[tid] += red[tid + off];
        __syncthreads();
    }
    if (tid == 0) out[g] = red[0] + b2[0];
}

// ---------------- launch ----------------

extern "C" void kernel_launch(void* const* d_in, const int* in_sizes, int n_in,
                              void* d_out, int out_size, void* d_ws, size_t ws_size,
                              hipStream_t stream) {
    const float* x     = (const float*)d_in[0];
    const int*   ei    = (const int*)d_in[1];     // [2,E]: src then dst
    const float* eattr = (const float*)d_in[2];
    const int*   batch = (const int*)d_in[3];
    const float* Wq    = (const float*)d_in[4];
    const float* Wk    = (const float*)d_in[5];
    const float* Wv    = (const float*)d_in[6];
    const float* We    = (const float*)d_in[7];
    const float* Wsk   = (const float*)d_in[8];
    const float* W1    = (const float*)d_in[9];
    const float* b1    = (const float*)d_in[10];
    const float* W2    = (const float*)d_in[11];
    const float* b2    = (const float*)d_in[12];
    float* out = (float*)d_out;

    const int* srcv = ei;
    const int* dstv = ei + NE;

    // workspace carve (float words; all bases 16B-aligned)
    float* ws = (float*)d_ws;
    size_t o = 0;
    float* Q    = ws + o; o += (size_t)NN * 64;
    uint*  KVp  = (uint*)(ws + o); o += (size_t)NN * 64;
    float* S    = ws + o; o += (size_t)NN * 64;
    float* QW   = ws + o; o += (size_t)NN * 64;
    float* H    = ws + o; o += (size_t)NN * 64;
    float* Mw   = ws + o; o += 5 * 4096;
    float* inv  = ws + o; o += GG;
    float* hcat = ws + o; o += GG * 320;
    int*   bstart = (int*)(ws + o); o += 68;
    // ---- zeroed region start ----
    int*   deg  = (int*)(ws + o); o += NN;
    int*   srcp = (int*)(ws + o); o += CSR_CAP;    // pad slots must be 0 (safe gathers)
    size_t zwords = (size_t)NN + CSR_CAP;
    // ---- zeroed region end ----
    int*    rank   = (int*)(ws + o); o += NE;
    int*    off    = (int*)(ws + o); o += NN;
    int*    locoff = (int*)(ws + o); o += NN;
    int*    bsum   = (int*)(ws + o); o += 128;
    ushort* aperm  = (ushort*)(ws + o); o += (size_t)CSR_CAP * 8;  // 16 ushorts/slot

    hipMemsetAsync(deg, 0, zwords * 4, stream);

    k_bounds<<<1, 128, 0, stream>>>(batch, bstart, inv);
    k_degrank<<<(NE + 255) / 256, 256, 0, stream>>>(dstv, deg, rank);
    k_scan1<<<SCAN_NB, SCAN_BLK, 0, stream>>>(deg, locoff, bsum);
    k_scan2<<<1, 128, 0, stream>>>(bsum);
    k_scan3<<<(NN + 255) / 256, 256, 0, stream>>>(locoff, bsum, off);
    k_fill<<<(NE + 255) / 256, 256, 0, stream>>>(srcv, dstv, eattr, off, rank, srcp, aperm);
    k_M<<<(5 * 4096 + 255) / 256, 256, 0, stream>>>(Wq, We, Mw);

    const float* hsrc = x;
    for (int l = 0; l < 5; ++l) {
        k_proj<<<(NN + 31) / 32, 256, 0, stream>>>(hsrc,
                                                   Wq + l * 4096, Wk + l * 4096,
                                                   Wv + l * 4096, Wsk + l * 4096,
                                                   Mw + l * 4096,
                                                   Q, KVp, S, QW);
        k_attn<<<(NN + 3) / 4, 256, 0, stream>>>(Q, KVp, S, QW,
                                                 We + l * 1024, aperm,
                                                 srcp, off, deg, H);
        k_pool<<<GG, 512, 0, stream>>>(H, bstart, inv, hcat, l);
        hsrc = H;
    }
    k_mlp<<<GG, 256, 0, stream>>>(hcat, W1, b1, W2, b2, out);
}

// Round 6
// 758.848 us; speedup vs baseline: 1.5960x; 1.0728x over previous
//
#include <hip/hip_runtime.h>
#include <math.h>

#define NN 50000
#define NE 800000
#define GG 64
#define SCAN_BLK 512
#define SCAN_NB ((NN + SCAN_BLK - 1) / SCAN_BLK)   // 98
#define CSR_CAP (NE + 4 * NN)                      // 4-aligned-per-node CSR capacity
#define PROJ_BLOCKS 512
#define NTILE ((NN + 31) / 32)                     // 1563

typedef unsigned int uint;
typedef unsigned short ushort;

__device__ __forceinline__ uint bf16r(float x) {   // RNE f32 -> bf16 bits
    uint u = __float_as_uint(x);
    return (u + 0x7fffu + ((u >> 16) & 1u)) >> 16;
}

// sum over each 16-lane group, result broadcast to all 16 lanes (pure DPP, no DS)
__device__ __forceinline__ float red16(float x) {
    float t;
    t = __int_as_float(__builtin_amdgcn_update_dpp(0, __float_as_int(x), 0xB1, 0xF, 0xF, 1)); // quad_perm xor1
    x += t;
    t = __int_as_float(__builtin_amdgcn_update_dpp(0, __float_as_int(x), 0x4E, 0xF, 0xF, 1)); // quad_perm xor2
    x += t;
    t = __int_as_float(__builtin_amdgcn_update_dpp(0, __float_as_int(x), 0x124, 0xF, 0xF, 1)); // row_ror:4
    x += t;
    t = __int_as_float(__builtin_amdgcn_update_dpp(0, __float_as_int(x), 0x128, 0xF, 0xF, 1)); // row_ror:8
    x += t;
    return x;
}

// ---------------- graph segment bounds (batch is sorted) ----------------

__global__ void k_bounds(const int* __restrict__ batch, int* __restrict__ bstart,
                         float* __restrict__ inv) {
    __shared__ int sb[65];
    int t = threadIdx.x;
    if (t <= 64) {
        int lo = 0, hi = NN;
        while (lo < hi) { int mid = (lo + hi) >> 1; if (batch[mid] < t) lo = mid + 1; else hi = mid; }
        sb[t] = lo;
        bstart[t] = lo;
    }
    __syncthreads();
    if (t < 64) inv[t] = 1.0f / fmaxf((float)(sb[t + 1] - sb[t]), 1.0f);
}

// ---------------- CSR build ----------------

__global__ __launch_bounds__(256) void k_degrank(const int* __restrict__ dstv,
                                                 int* __restrict__ deg,
                                                 int* __restrict__ rank) {
    int e = blockIdx.x * 256 + threadIdx.x;
    if (e < NE) rank[e] = atomicAdd(&deg[dstv[e]], 1);
}

__global__ __launch_bounds__(SCAN_BLK) void k_scan1(const int* __restrict__ deg,
                                                    int* __restrict__ locoff,
                                                    int* __restrict__ bsum) {
    __shared__ int sh[SCAN_BLK];
    int tid = threadIdx.x;
    int n = blockIdx.x * SCAN_BLK + tid;
    int v = (n < NN) ? ((deg[n] + 3) & ~3) : 0;
    sh[tid] = v;
    __syncthreads();
    for (int off = 1; off < SCAN_BLK; off <<= 1) {
        int t = (tid >= off) ? sh[tid - off] : 0;
        __syncthreads();
        sh[tid] += t;
        __syncthreads();
    }
    if (n < NN) locoff[n] = sh[tid] - v;   // exclusive
    if (tid == SCAN_BLK - 1) bsum[blockIdx.x] = sh[tid];
}

__global__ void k_scan2(int* __restrict__ bsum) {
    __shared__ int sh[128];
    int t = threadIdx.x;
    int v = (t < SCAN_NB) ? bsum[t] : 0;
    sh[t] = v;
    __syncthreads();
    for (int off = 1; off < 128; off <<= 1) {
        int u = (t >= off) ? sh[t - off] : 0;
        __syncthreads();
        sh[t] += u;
        __syncthreads();
    }
    if (t < SCAN_NB) bsum[t] = sh[t] - v;  // exclusive
}

__global__ __launch_bounds__(256) void k_scan3(const int* __restrict__ locoff,
                                               const int* __restrict__ bsum,
                                               int* __restrict__ off) {
    int n = blockIdx.x * 256 + threadIdx.x;
    if (n < NN) off[n] = locoff[n] + bsum[n >> 9];
}

// fill srcp (as BYTE offsets into KVp rows) + CSR-ordered bf16 attrs
__global__ __launch_bounds__(256) void k_fill(const int* __restrict__ srcv,
                                              const int* __restrict__ dstv,
                                              const float* __restrict__ eattr,
                                              const int* __restrict__ off,
                                              const int* __restrict__ rank,
                                              int* __restrict__ srcp,
                                              ushort* __restrict__ aperm) {
    int e = blockIdx.x * 256 + threadIdx.x;
    if (e >= NE) return;
    int d = dstv[e];
    int p = off[d] + rank[e];
    srcp[p] = srcv[e] << 8;                 // 256 B per KVp row
    const float4* ea = reinterpret_cast<const float4*>(eattr + (size_t)e * 16);
    float4 a = ea[0], b = ea[1], c = ea[2], d4 = ea[3];
    uint4 u0, u1;
    u0.x = bf16r(a.x) | (bf16r(a.y) << 16);
    u0.y = bf16r(a.z) | (bf16r(a.w) << 16);
    u0.z = bf16r(b.x) | (bf16r(b.y) << 16);
    u0.w = bf16r(b.z) | (bf16r(b.w) << 16);
    u1.x = bf16r(c.x) | (bf16r(c.y) << 16);
    u1.y = bf16r(c.z) | (bf16r(c.w) << 16);
    u1.z = bf16r(d4.x) | (bf16r(d4.y) << 16);
    u1.w = bf16r(d4.z) | (bf16r(d4.w) << 16);
    uint4* ap = reinterpret_cast<uint4*>(aperm + (size_t)p * 16);
    ap[0] = u0;
    ap[1] = u1;
}

// M[l][i][c] = sum_dd Wq[l][i][h*16+dd] * We[l][j][h*16+dd],  c = h*16+j
__global__ __launch_bounds__(256) void k_M(const float* __restrict__ Wq,
                                           const float* __restrict__ We,
                                           float* __restrict__ M) {
    int t = blockIdx.x * 256 + threadIdx.x;
    if (t >= 5 * 64 * 64) return;
    int l = t >> 12, i = (t >> 6) & 63, c = t & 63;
    int hh = c >> 4, j = c & 15;
    const float* wq = Wq + l * 4096 + i * 64 + hh * 16;
    const float* we = We + l * 1024 + j * 64 + hh * 16;
    float acc = 0.f;
#pragma unroll
    for (int dd = 0; dd < 16; ++dd) acc += wq[dd] * we[dd];
    M[t] = acc;
}

// ---------------- fused projections, persistent: weights staged ONCE per block ----------------
// grid = 512 blocks (2/CU), each grid-strides over 32-node tiles

__global__ __launch_bounds__(256) void k_proj(const float* __restrict__ hsrc,
                                              const float* __restrict__ Wq,
                                              const float* __restrict__ Wk,
                                              const float* __restrict__ Wv,
                                              const float* __restrict__ Wsk,
                                              const float* __restrict__ Mw,
                                              float* __restrict__ Q,
                                              uint* __restrict__ KVp,
                                              float* __restrict__ S,
                                              float* __restrict__ QW) {
    __shared__ float wT[4096 * 4];   // [k*64+c][{q,k,v,sk}], 64 KB, read as b128
    __shared__ float hT[32 * 64];    // 8 KB node tile
    int tid = threadIdx.x;
    for (int i4 = tid * 4; i4 < 4096; i4 += 1024) {
        float4 a = *reinterpret_cast<const float4*>(Wq + i4);
        float4 b = *reinterpret_cast<const float4*>(Wk + i4);
        float4 c = *reinterpret_cast<const float4*>(Wv + i4);
        float4 d = *reinterpret_cast<const float4*>(Wsk + i4);
        *reinterpret_cast<float4*>(&wT[(i4 + 0) * 4]) = make_float4(a.x, b.x, c.x, d.x);
        *reinterpret_cast<float4*>(&wT[(i4 + 1) * 4]) = make_float4(a.y, b.y, c.y, d.y);
        *reinterpret_cast<float4*>(&wT[(i4 + 2) * 4]) = make_float4(a.z, b.z, c.z, d.z);
        *reinterpret_cast<float4*>(&wT[(i4 + 3) * 4]) = make_float4(a.w, b.w, c.w, d.w);
    }

    int lane = tid & 63, wv = tid >> 6;
    int hbase = wv * 8 * 64;

    for (int tile = blockIdx.x; tile < NTILE; tile += gridDim.x) {
        int nb0 = tile * 32;
        __syncthreads();   // previous tile's compute done (and, first time, wT staged)
        for (int i4 = tid * 4; i4 < 2048; i4 += 1024) {
            size_t gi = (size_t)nb0 * 64 + i4;
            if (gi + 3 < (size_t)NN * 64) {
                *reinterpret_cast<float4*>(&hT[i4]) = *reinterpret_cast<const float4*>(hsrc + gi);
            } else {
#pragma unroll
                for (int j = 0; j < 4; ++j)
                    hT[i4 + j] = (gi + j < (size_t)NN * 64) ? hsrc[gi + j] : 0.f;
            }
        }
        __syncthreads();

        float acc[8][5];
#pragma unroll
        for (int i = 0; i < 8; ++i)
#pragma unroll
            for (int m = 0; m < 5; ++m) acc[i][m] = 0.f;

        for (int k = 0; k < 64; k += 4) {
            float4 hreg[8];
#pragma unroll
            for (int i = 0; i < 8; ++i)
                hreg[i] = *reinterpret_cast<const float4*>(&hT[hbase + i * 64 + k]);
#pragma unroll
            for (int kk = 0; kk < 4; ++kk) {
                float4 w = *reinterpret_cast<const float4*>(&wT[((k + kk) * 64 + lane) * 4]);
                float wm = Mw[(k + kk) * 64 + lane];
#pragma unroll
                for (int i = 0; i < 8; ++i) {
                    float hv = reinterpret_cast<const float*>(&hreg[i])[kk];
                    acc[i][0] = fmaf(hv, w.x, acc[i][0]);
                    acc[i][1] = fmaf(hv, w.y, acc[i][1]);
                    acc[i][2] = fmaf(hv, w.z, acc[i][2]);
                    acc[i][3] = fmaf(hv, w.w, acc[i][3]);
                    acc[i][4] = fmaf(hv, wm,  acc[i][4]);
                }
            }
        }
#pragma unroll
        for (int i = 0; i < 8; ++i) {
            int node = nb0 + wv * 8 + i;
            if (node < NN) {
                int base = node * 64 + lane;
                Q[base]   = acc[i][0];
                KVp[base] = (bf16r(acc[i][1]) << 16) | bf16r(acc[i][2]);  // K hi, V lo
                S[base]   = acc[i][3];
                QW[base]  = acc[i][4];
            }
        }
    }
}

// ---------------- per-node online-softmax attention + relu (NO atomics, NO DS in hot loop) ----------------
// block=256 (4 waves), one node per wave; 4-edge batches, 2-stage pipeline,
// DPP 16-lane reduce, exp2 domain, byte-offset gathers

__global__ __launch_bounds__(256) void k_attn(const float* __restrict__ Q,
                                              const uint* __restrict__ KVp,
                                              const float* __restrict__ S,
                                              const float* __restrict__ QW,
                                              const float* __restrict__ Wel,
                                              const ushort* __restrict__ aperm,
                                              const int* __restrict__ srcp,
                                              const int* __restrict__ offp,
                                              const int* __restrict__ cnt,
                                              float* __restrict__ Hout) {
    __shared__ float we[16 * 64];   // 4 KB
    int tid = threadIdx.x;
    for (int i = tid; i < 1024; i += 256) we[i] = Wel[i];
    __syncthreads();

    int lane = tid & 63;
    int n = blockIdx.x * 4 + (tid >> 6);
    if (n >= NN) return;

    int dd = lane & 15;     // channel within head
    int hg = lane >> 4;     // head

    const float C2 = 0.36067376022224085f;   // ATT_SCALE * log2(e)
    float q  = Q[n * 64 + lane] * C2;
    float qw = QW[n * 64 + lane] * C2;
    int dg   = cnt[n];
    int pos0 = offp[n];
    int nbt  = (dg + 3) >> 2;

    const char* kvb = (const char*)KVp + lane * 4;
    const ushort* apb = aperm + (size_t)pos0 * 16 + dd;

    float m = -1e30f, s = 0.f, av = 0.f, aa = 0.f;

    auto ldidx = [&](int b, int4& sn) {
        sn = (b < nbt) ? *reinterpret_cast<const int4*>(srcp + pos0 + b * 4)
                       : make_int4(0, 0, 0, 0);
    };
    auto issue = [&](int b, const int4& sn, uint (&kv)[4], uint (&au)[4]) {
        kv[0] = *reinterpret_cast<const uint*>(kvb + sn.x);
        kv[1] = *reinterpret_cast<const uint*>(kvb + sn.y);
        kv[2] = *reinterpret_cast<const uint*>(kvb + sn.z);
        kv[3] = *reinterpret_cast<const uint*>(kvb + sn.w);
        const ushort* ap = apb + (size_t)b * 64;
        au[0] = ap[0];
        au[1] = ap[16];
        au[2] = ap[32];
        au[3] = ap[48];
    };
    auto compute = [&](int b, const uint (&kv)[4], const uint (&au)[4]) {
        int rem = dg - b * 4;
        float l[4], vf[4], af[4];
#pragma unroll
        for (int j = 0; j < 4; ++j) {
            uint w = kv[j];
            float kf = __uint_as_float(w & 0xffff0000u);
            vf[j] = __uint_as_float(w << 16);
            af[j] = __uint_as_float(au[j] << 16);
            float p = fmaf(q, kf, qw * af[j]);   // scale pre-folded into q,qw (log2 domain)
            p = red16(p);
            l[j] = (j < rem) ? p : -1e30f;
        }
        float bm = fmaxf(fmaxf(l[0], l[1]), fmaxf(l[2], l[3]));
        float mn = fmaxf(m, bm);
        float wold = __builtin_amdgcn_exp2f(m - mn);
        float a0 = __builtin_amdgcn_exp2f(l[0] - mn);
        float a1 = __builtin_amdgcn_exp2f(l[1] - mn);
        float a2 = __builtin_amdgcn_exp2f(l[2] - mn);
        float a3 = __builtin_amdgcn_exp2f(l[3] - mn);
        s  = fmaf(s,  wold, (a0 + a1) + (a2 + a3));
        av = fmaf(av, wold, fmaf(a0, vf[0], fmaf(a1, vf[1], fmaf(a2, vf[2], a3 * vf[3]))));
        aa = fmaf(aa, wold, fmaf(a0, af[0], fmaf(a1, af[1], fmaf(a2, af[2], a3 * af[3]))));
        m = mn;
    };

    int4 sn0, sn1;
    uint kv0[4], kv1[4], at0[4], at1[4];

    ldidx(0, sn0);
    issue(0, sn0, kv0, at0);
    ldidx(1, sn1);

    int b = 0;
    while (b + 1 < nbt) {
        issue(b + 1, sn1, kv1, at1);          // gathers for batch b+1
        ldidx(b + 2, sn0);                    // indices for batch b+2
        compute(b, kv0, at0);
        if (b + 2 < nbt) {
            issue(b + 2, sn0, kv0, at0);      // gathers for batch b+2
            ldidx(b + 3, sn1);                // indices for batch b+3
        }
        compute(b + 1, kv1, at1);
        b += 2;
    }
    if (b < nbt) compute(b, kv0, at0);

    float rden = 1.0f / (s + 1e-16f);
    float eagg = 0.f;
#pragma unroll
    for (int j = 0; j < 16; ++j) {
        float aj = __shfl(aa, hg * 16 + j, 64);
        eagg = fmaf(aj, we[j * 64 + lane], eagg);
    }
    float agg = (av + eagg) * rden;
    Hout[n * 64 + lane] = fmaxf(agg + S[n * 64 + lane], 0.f);
}

// ---------------- mean pool one layer: 64 blocks (one per graph), contiguous rows ----------------

__global__ __launch_bounds__(512) void k_pool(const float* __restrict__ H,
                                              const int* __restrict__ bstart,
                                              const float* __restrict__ inv,
                                              float* __restrict__ hcat,
                                              int layer) {
    __shared__ float red[512];
    int g = blockIdx.x;
    int lo = bstart[g], hi = bstart[g + 1];
    int ch = threadIdx.x & 63, ro = threadIdx.x >> 6;   // 8 row stripes
    float acc = 0.f;
    for (int r = lo + ro; r < hi; r += 8) acc += H[(size_t)r * 64 + ch];
    red[threadIdx.x] = acc;
    __syncthreads();
    if (ro < 4) red[threadIdx.x] += red[threadIdx.x + 256];
    __syncthreads();
    if (ro < 2) red[threadIdx.x] += red[threadIdx.x + 128];
    __syncthreads();
    if (ro == 0)
        hcat[g * 320 + layer * 64 + ch] = (red[ch] + red[64 + ch]) * inv[g];
}

// ---------------- final MLP: one block per graph ----------------

__global__ __launch_bounds__(256) void k_mlp(const float* __restrict__ hcat,
                                             const float* __restrict__ W1,
                                             const float* __restrict__ b1,
                                             const float* __restrict__ W2,
                                             const float* __restrict__ b2,
                                             float* __restrict__ out) {
    __shared__ float hc[320];
    __shared__ float red[256];
    int g = blockIdx.x, tid = threadIdx.x;
    for (int i = tid; i < 320; i += 256) hc[i] = hcat[g * 320 + i];
    __syncthreads();
    float part = 0.f;
    for (int j = tid; j < 320; j += 256) {
        float t = b1[j];
        for (int k = 0; k < 320; ++k) t = fmaf(hc[k], W1[k * 320 + j], t);
        part = fmaf(fmaxf(t, 0.f), W2[j], part);
    }
    red[tid] = part;
    __syncthreads();
    for (int off = 128; off > 0; off >>= 1) {
        if (tid < off) red[tid] += red[tid + off];
        __syncthreads();
    }
    if (tid == 0) out[g] = red[0] + b2[0];
}

// ---------------- launch ----------------

extern "C" void kernel_launch(void* const* d_in, const int* in_sizes, int n_in,
                              void* d_out, int out_size, void* d_ws, size_t ws_size,
                              hipStream_t stream) {
    const float* x     = (const float*)d_in[0];
    const int*   ei    = (const int*)d_in[1];     // [2,E]: src then dst
    const float* eattr = (const float*)d_in[2];
    const int*   batch = (const int*)d_in[3];
    const float* Wq    = (const float*)d_in[4];
    const float* Wk    = (const float*)d_in[5];
    const float* Wv    = (const float*)d_in[6];
    const float* We    = (const float*)d_in[7];
    const float* Wsk   = (const float*)d_in[8];
    const float* W1    = (const float*)d_in[9];
    const float* b1    = (const float*)d_in[10];
    const float* W2    = (const float*)d_in[11];
    const float* b2    = (const float*)d_in[12];
    float* out = (float*)d_out;

    const int* srcv = ei;
    const int* dstv = ei + NE;

    // workspace carve (float words; all bases 16B-aligned)
    float* ws = (float*)d_ws;
    size_t o = 0;
    float* Q    = ws + o; o += (size_t)NN * 64;
    uint*  KVp  = (uint*)(ws + o); o += (size_t)NN * 64;
    float* S    = ws + o; o += (size_t)NN * 64;
    float* QW   = ws + o; o += (size_t)NN * 64;
    float* H    = ws + o; o += (size_t)NN * 64;
    float* Mw   = ws + o; o += 5 * 4096;
    float* inv  = ws + o; o += GG;
    float* hcat = ws + o; o += GG * 320;
    int*   bstart = (int*)(ws + o); o += 68;
    // ---- zeroed region start ----
    int*   deg  = (int*)(ws + o); o += NN;
    int*   srcp = (int*)(ws + o); o += CSR_CAP;    // pad slots must be 0 (safe gathers)
    size_t zwords = (size_t)NN + CSR_CAP;
    // ---- zeroed region end ----
    int*    rank   = (int*)(ws + o); o += NE;
    int*    off    = (int*)(ws + o); o += NN;
    int*    locoff = (int*)(ws + o); o += NN;
    int*    bsum   = (int*)(ws + o); o += 128;
    ushort* aperm  = (ushort*)(ws + o); o += (size_t)CSR_CAP * 8 + 64;  // 16 ushorts/slot

    hipMemsetAsync(deg, 0, zwords * 4, stream);

    k_bounds<<<1, 128, 0, stream>>>(batch, bstart, inv);
    k_degrank<<<(NE + 255) / 256, 256, 0, stream>>>(dstv, deg, rank);
    k_scan1<<<SCAN_NB, SCAN_BLK, 0, stream>>>(deg, locoff, bsum);
    k_scan2<<<1, 128, 0, stream>>>(bsum);
    k_scan3<<<(NN + 255) / 256, 256, 0, stream>>>(locoff, bsum, off);
    k_fill<<<(NE + 255) / 256, 256, 0, stream>>>(srcv, dstv, eattr, off, rank, srcp, aperm);
    k_M<<<(5 * 4096 + 255) / 256, 256, 0, stream>>>(Wq, We, Mw);

    const float* hsrc = x;
    for (int l = 0; l < 5; ++l) {
        k_proj<<<PROJ_BLOCKS, 256, 0, stream>>>(hsrc,
                                                Wq + l * 4096, Wk + l * 4096,
                                                Wv + l * 4096, Wsk + l * 4096,
                                                Mw + l * 4096,
                                                Q, KVp, S, QW);
        k_attn<<<(NN + 3) / 4, 256, 0, stream>>>(Q, KVp, S, QW,
                                                 We + l * 1024, aperm,
                                                 srcp, off, deg, H);
        k_pool<<<GG, 512, 0, stream>>>(H, bstart, inv, hcat, l);
        hsrc = H;
    }
    k_mlp<<<GG, 256, 0, stream>>>(hcat, W1, b1, W2, b2, out);
}

// Round 7
// 516.232 us; speedup vs baseline: 2.3461x; 1.4700x over previous
//
#include <hip/hip_runtime.h>
#include <math.h>

#define NN 50000
#define NE 800000
#define GG 64
#define SCAN_BLK 512
#define SCAN_NB ((NN + SCAN_BLK - 1) / SCAN_BLK)   // 98
#define CSR_CAP (NE + 4 * NN)                      // 4-aligned-per-node CSR capacity
#define NBLK ((NN + 63) / 64)                      // 782 proj blocks

typedef unsigned int uint;
typedef unsigned short ushort;
typedef __attribute__((ext_vector_type(8))) short short8v;  // 8 bf16 (4 VGPRs)
typedef __attribute__((ext_vector_type(4))) float f32x4;

__device__ __forceinline__ uint bf16r(float x) {   // RNE f32 -> bf16 bits
    uint u = __float_as_uint(x);
    return (u + 0x7fffu + ((u >> 16) & 1u)) >> 16;
}

// sum over each 16-lane group, result broadcast to all 16 lanes (pure DPP, no DS)
__device__ __forceinline__ float red16(float x) {
    float t;
    t = __int_as_float(__builtin_amdgcn_update_dpp(0, __float_as_int(x), 0xB1, 0xF, 0xF, 1)); // quad_perm xor1
    x += t;
    t = __int_as_float(__builtin_amdgcn_update_dpp(0, __float_as_int(x), 0x4E, 0xF, 0xF, 1)); // quad_perm xor2
    x += t;
    t = __int_as_float(__builtin_amdgcn_update_dpp(0, __float_as_int(x), 0x124, 0xF, 0xF, 1)); // row_ror:4
    x += t;
    t = __int_as_float(__builtin_amdgcn_update_dpp(0, __float_as_int(x), 0x128, 0xF, 0xF, 1)); // row_ror:8
    x += t;
    return x;
}

// ---------------- graph segment bounds (batch is sorted) ----------------

__global__ void k_bounds(const int* __restrict__ batch, int* __restrict__ bstart,
                         float* __restrict__ inv) {
    __shared__ int sb[65];
    int t = threadIdx.x;
    if (t <= 64) {
        int lo = 0, hi = NN;
        while (lo < hi) { int mid = (lo + hi) >> 1; if (batch[mid] < t) lo = mid + 1; else hi = mid; }
        sb[t] = lo;
        bstart[t] = lo;
    }
    __syncthreads();
    if (t < 64) inv[t] = 1.0f / fmaxf((float)(sb[t + 1] - sb[t]), 1.0f);
}

// ---------------- CSR build ----------------

__global__ __launch_bounds__(256) void k_degrank(const int* __restrict__ dstv,
                                                 int* __restrict__ deg,
                                                 int* __restrict__ rank) {
    int e = blockIdx.x * 256 + threadIdx.x;
    if (e < NE) rank[e] = atomicAdd(&deg[dstv[e]], 1);
}

__global__ __launch_bounds__(SCAN_BLK) void k_scan1(const int* __restrict__ deg,
                                                    int* __restrict__ locoff,
                                                    int* __restrict__ bsum) {
    __shared__ int sh[SCAN_BLK];
    int tid = threadIdx.x;
    int n = blockIdx.x * SCAN_BLK + tid;
    int v = (n < NN) ? ((deg[n] + 3) & ~3) : 0;
    sh[tid] = v;
    __syncthreads();
    for (int off = 1; off < SCAN_BLK; off <<= 1) {
        int t = (tid >= off) ? sh[tid - off] : 0;
        __syncthreads();
        sh[tid] += t;
        __syncthreads();
    }
    if (n < NN) locoff[n] = sh[tid] - v;   // exclusive
    if (tid == SCAN_BLK - 1) bsum[blockIdx.x] = sh[tid];
}

__global__ void k_scan2(int* __restrict__ bsum) {
    __shared__ int sh[128];
    int t = threadIdx.x;
    int v = (t < SCAN_NB) ? bsum[t] : 0;
    sh[t] = v;
    __syncthreads();
    for (int off = 1; off < 128; off <<= 1) {
        int u = (t >= off) ? sh[t - off] : 0;
        __syncthreads();
        sh[t] += u;
        __syncthreads();
    }
    if (t < SCAN_NB) bsum[t] = sh[t] - v;  // exclusive
}

__global__ __launch_bounds__(256) void k_scan3(const int* __restrict__ locoff,
                                               const int* __restrict__ bsum,
                                               int* __restrict__ off) {
    int n = blockIdx.x * 256 + threadIdx.x;
    if (n < NN) off[n] = locoff[n] + bsum[n >> 9];
}

// fill srcp (as BYTE offsets into KVp rows) + CSR-ordered bf16 attrs
__global__ __launch_bounds__(256) void k_fill(const int* __restrict__ srcv,
                                              const int* __restrict__ dstv,
                                              const float* __restrict__ eattr,
                                              const int* __restrict__ off,
                                              const int* __restrict__ rank,
                                              int* __restrict__ srcp,
                                              ushort* __restrict__ aperm) {
    int e = blockIdx.x * 256 + threadIdx.x;
    if (e >= NE) return;
    int d = dstv[e];
    int p = off[d] + rank[e];
    srcp[p] = srcv[e] << 8;                 // 256 B per KVp row
    const float4* ea = reinterpret_cast<const float4*>(eattr + (size_t)e * 16);
    float4 a = ea[0], b = ea[1], c = ea[2], d4 = ea[3];
    uint4 u0, u1;
    u0.x = bf16r(a.x) | (bf16r(a.y) << 16);
    u0.y = bf16r(a.z) | (bf16r(a.w) << 16);
    u0.z = bf16r(b.x) | (bf16r(b.y) << 16);
    u0.w = bf16r(b.z) | (bf16r(b.w) << 16);
    u1.x = bf16r(c.x) | (bf16r(c.y) << 16);
    u1.y = bf16r(c.z) | (bf16r(c.w) << 16);
    u1.z = bf16r(d4.x) | (bf16r(d4.y) << 16);
    u1.w = bf16r(d4.z) | (bf16r(d4.w) << 16);
    uint4* ap = reinterpret_cast<uint4*>(aperm + (size_t)p * 16);
    ap[0] = u0;
    ap[1] = u1;
}

// M[l][i][c] = sum_dd Wq[l][i][h*16+dd] * We[l][j][h*16+dd],  c = h*16+j
__global__ __launch_bounds__(256) void k_M(const float* __restrict__ Wq,
                                           const float* __restrict__ We,
                                           float* __restrict__ M) {
    int t = blockIdx.x * 256 + threadIdx.x;
    if (t >= 5 * 64 * 64) return;
    int l = t >> 12, i = (t >> 6) & 63, c = t & 63;
    int hh = c >> 4, j = c & 15;
    const float* wq = Wq + l * 4096 + i * 64 + hh * 16;
    const float* we = We + l * 1024 + j * 64 + hh * 16;
    float acc = 0.f;
#pragma unroll
    for (int dd = 0; dd < 16; ++dd) acc += wq[dd] * we[dd];
    M[t] = acc;
}

// ---------------- pack combined weight matrix into MFMA B-fragment order ----------------
// Wall[64k][320c] = [Wq|Wk|Wv|Wsk|M] per layer; frag (nt,s): lane l holds
// B[k = s*32 + 8*(l>>4) + j][c = nt*16 + (l&15)], j=0..7 -> Wf[l][nt][s][l][j] bf16

__global__ __launch_bounds__(256) void k_wfrag(const float* __restrict__ Wq,
                                               const float* __restrict__ Wk,
                                               const float* __restrict__ Wv,
                                               const float* __restrict__ Wsk,
                                               const float* __restrict__ Mw,
                                               ushort* __restrict__ Wf) {
    int t = blockIdx.x * 256 + threadIdx.x;
    if (t >= 5 * 20 * 2 * 64) return;
    int l = t / (20 * 2 * 64);
    int rem = t % (20 * 2 * 64);
    int nt = rem >> 7, s = (rem >> 6) & 1, lane = rem & 63;
    int c = nt * 16 + (lane & 15);
    int k0 = s * 32 + 8 * (lane >> 4);
    int msel = c >> 6, cc = c & 63;
    const float* W = (msel == 0) ? Wq + l * 4096 :
                     (msel == 1) ? Wk + l * 4096 :
                     (msel == 2) ? Wv + l * 4096 :
                     (msel == 3) ? Wsk + l * 4096 : Mw + l * 4096;
    ushort o[8];
#pragma unroll
    for (int j = 0; j < 8; ++j) o[j] = (ushort)bf16r(W[(k0 + j) * 64 + cc]);
    uint4* dst = reinterpret_cast<uint4*>(Wf + (size_t)t * 8);
    uint4 u;
    u.x = (uint)o[0] | ((uint)o[1] << 16);
    u.y = (uint)o[2] | ((uint)o[3] << 16);
    u.z = (uint)o[4] | ((uint)o[5] << 16);
    u.w = (uint)o[6] | ((uint)o[7] << 16);
    dst[0] = u;
}

// ---------------- MFMA projection: [64 nodes] x [64] @ [64 x 320], LDS-free ----------------
// 4 waves; wave w owns 16-channel slice ch = w*16+(lane&15) of all 5 outputs.
// A: row=lane&15, k=8*(lane>>4)+j (per 16x16x32 bf16 frag); C/D: col=lane&15, row=(lane>>4)*4+reg.

template<bool L0>
__global__ __launch_bounds__(256) void k_projm(const float* __restrict__ x,
                                               const ushort* __restrict__ Hin,
                                               const ushort* __restrict__ Wfl,
                                               uint* __restrict__ QQp,
                                               uint* __restrict__ KVp,
                                               float* __restrict__ Sb) {
    int tid = threadIdx.x, lane = tid & 63, wv = tid >> 6;
    int n0 = blockIdx.x * 64;
    int arow = lane & 15, agrp = lane >> 4;

    short8v A[4][2];
#pragma unroll
    for (int mt = 0; mt < 4; ++mt) {
        int node = n0 + mt * 16 + arow;
        if (node >= NN) node = NN - 1;        // clamped load; stores guarded below
#pragma unroll
        for (int s = 0; s < 2; ++s) {
            int k0 = s * 32 + agrp * 8;
            if (L0) {
                const float* hp = x + (size_t)node * 64 + k0;
                float4 u = *reinterpret_cast<const float4*>(hp);
                float4 v = *reinterpret_cast<const float4*>(hp + 4);
                short8v a;
                a[0] = (short)bf16r(u.x); a[1] = (short)bf16r(u.y);
                a[2] = (short)bf16r(u.z); a[3] = (short)bf16r(u.w);
                a[4] = (short)bf16r(v.x); a[5] = (short)bf16r(v.y);
                a[6] = (short)bf16r(v.z); a[7] = (short)bf16r(v.w);
                A[mt][s] = a;
            } else {
                A[mt][s] = *reinterpret_cast<const short8v*>(Hin + (size_t)node * 64 + k0);
            }
        }
    }

    int ch = wv * 16 + arow;
    int rb = agrp * 4;
    f32x4 qh[4], kh[4];
    const f32x4 z = {0.f, 0.f, 0.f, 0.f};

#pragma unroll
    for (int ni = 0; ni < 5; ++ni) {
        int ntl = wv + 4 * ni;   // col-tile: ni selects {Q,K,V,Sk,QW}, wv the 16-ch slice
        f32x4 acc[4] = {z, z, z, z};
#pragma unroll
        for (int s = 0; s < 2; ++s) {
            short8v B = *reinterpret_cast<const short8v*>(
                Wfl + (((size_t)ntl * 2 + s) * 64 + lane) * 8);
#pragma unroll
            for (int mt = 0; mt < 4; ++mt)
                acc[mt] = __builtin_amdgcn_mfma_f32_16x16x32_bf16(A[mt][s], B, acc[mt], 0, 0, 0);
        }
        if (ni == 0) {
#pragma unroll
            for (int mt = 0; mt < 4; ++mt) qh[mt] = acc[mt];
        } else if (ni == 1) {
#pragma unroll
            for (int mt = 0; mt < 4; ++mt) kh[mt] = acc[mt];
        } else if (ni == 2) {            // V ready: pack K|V
#pragma unroll
            for (int mt = 0; mt < 4; ++mt)
#pragma unroll
                for (int r = 0; r < 4; ++r) {
                    int node = n0 + mt * 16 + rb + r;
                    if (node < NN)
                        KVp[(size_t)node * 64 + ch] = (bf16r(kh[mt][r]) << 16) | bf16r(acc[mt][r]);
                }
        } else if (ni == 3) {            // skip projection, f32
#pragma unroll
            for (int mt = 0; mt < 4; ++mt)
#pragma unroll
                for (int r = 0; r < 4; ++r) {
                    int node = n0 + mt * 16 + rb + r;
                    if (node < NN) Sb[(size_t)node * 64 + ch] = acc[mt][r];
                }
        } else {                          // QW ready: pack Q|QW
#pragma unroll
            for (int mt = 0; mt < 4; ++mt)
#pragma unroll
                for (int r = 0; r < 4; ++r) {
                    int node = n0 + mt * 16 + rb + r;
                    if (node < NN)
                        QQp[(size_t)node * 64 + ch] = (bf16r(qh[mt][r]) << 16) | bf16r(acc[mt][r]);
                }
        }
    }
}

// ---------------- per-node online-softmax attention + relu ----------------
// block=256 (4 waves), one node per wave; 4-edge batches, 2-stage pipeline,
// DPP 16-lane reduce, exp2 domain, byte-offset gathers; bf16 H output

__global__ __launch_bounds__(256) void k_attn(const uint* __restrict__ QQp,
                                              const uint* __restrict__ KVp,
                                              const float* __restrict__ Sb,
                                              const float* __restrict__ Wel,
                                              const ushort* __restrict__ aperm,
                                              const int* __restrict__ srcp,
                                              const int* __restrict__ offp,
                                              const int* __restrict__ cnt,
                                              ushort* __restrict__ Hout) {
    __shared__ float we[16 * 64];   // 4 KB
    int tid = threadIdx.x;
    for (int i = tid; i < 1024; i += 256) we[i] = Wel[i];
    __syncthreads();

    int lane = tid & 63;
    int n = blockIdx.x * 4 + (tid >> 6);
    if (n >= NN) return;

    int dd = lane & 15;     // channel within head
    int hg = lane >> 4;     // head

    const float C2 = 0.36067376022224085f;   // 0.25 * log2(e)
    uint qq = QQp[n * 64 + lane];
    float q  = __uint_as_float(qq & 0xffff0000u) * C2;
    float qw = __uint_as_float(qq << 16) * C2;
    int dg   = cnt[n];
    int pos0 = offp[n];
    int nbt  = (dg + 3) >> 2;

    const char* kvb = (const char*)KVp + lane * 4;
    const ushort* apb = aperm + (size_t)pos0 * 16 + dd;

    float m = -1e30f, s = 0.f, av = 0.f, aa = 0.f;

    auto ldidx = [&](int b, int4& sn) {
        sn = (b < nbt) ? *reinterpret_cast<const int4*>(srcp + pos0 + b * 4)
                       : make_int4(0, 0, 0, 0);
    };
    auto issue = [&](int b, const int4& sn, uint (&kv)[4], uint (&au)[4]) {
        kv[0] = *reinterpret_cast<const uint*>(kvb + sn.x);
        kv[1] = *reinterpret_cast<const uint*>(kvb + sn.y);
        kv[2] = *reinterpret_cast<const uint*>(kvb + sn.z);
        kv[3] = *reinterpret_cast<const uint*>(kvb + sn.w);
        const ushort* ap = apb + (size_t)b * 64;
        au[0] = ap[0];
        au[1] = ap[16];
        au[2] = ap[32];
        au[3] = ap[48];
    };
    auto compute = [&](int b, const uint (&kv)[4], const uint (&au)[4]) {
        int rem = dg - b * 4;
        float l[4], vf[4], af[4];
#pragma unroll
        for (int j = 0; j < 4; ++j) {
            uint w = kv[j];
            float kf = __uint_as_float(w & 0xffff0000u);
            vf[j] = __uint_as_float(w << 16);
            af[j] = __uint_as_float(au[j] << 16);
            float p = fmaf(q, kf, qw * af[j]);   // scale pre-folded into q,qw (log2 domain)
            p = red16(p);
            l[j] = (j < rem) ? p : -1e30f;
        }
        float bm = fmaxf(fmaxf(l[0], l[1]), fmaxf(l[2], l[3]));
        float mn = fmaxf(m, bm);
        float wold = __builtin_amdgcn_exp2f(m - mn);
        float a0 = __builtin_amdgcn_exp2f(l[0] - mn);
        float a1 = __builtin_amdgcn_exp2f(l[1] - mn);
        float a2 = __builtin_amdgcn_exp2f(l[2] - mn);
        float a3 = __builtin_amdgcn_exp2f(l[3] - mn);
        s  = fmaf(s,  wold, (a0 + a1) + (a2 + a3));
        av = fmaf(av, wold, fmaf(a0, vf[0], fmaf(a1, vf[1], fmaf(a2, vf[2], a3 * vf[3]))));
        aa = fmaf(aa, wold, fmaf(a0, af[0], fmaf(a1, af[1], fmaf(a2, af[2], a3 * af[3]))));
        m = mn;
    };

    int4 sn0, sn1;
    uint kv0[4], kv1[4], at0[4], at1[4];

    ldidx(0, sn0);
    issue(0, sn0, kv0, at0);
    ldidx(1, sn1);

    int b = 0;
    while (b + 1 < nbt) {
        issue(b + 1, sn1, kv1, at1);          // gathers for batch b+1
        ldidx(b + 2, sn0);                    // indices for batch b+2
        compute(b, kv0, at0);
        if (b + 2 < nbt) {
            issue(b + 2, sn0, kv0, at0);      // gathers for batch b+2
            ldidx(b + 3, sn1);                // indices for batch b+3
        }
        compute(b + 1, kv1, at1);
        b += 2;
    }
    if (b < nbt) compute(b, kv0, at0);

    float rden = 1.0f / (s + 1e-16f);
    float eagg = 0.f;
#pragma unroll
    for (int j = 0; j < 16; ++j) {
        float aj = __shfl(aa, hg * 16 + j, 64);
        eagg = fmaf(aj, we[j * 64 + lane], eagg);
    }
    float agg = (av + eagg) * rden;
    float hn = fmaxf(agg + Sb[n * 64 + lane], 0.f);
    Hout[(size_t)n * 64 + lane] = (ushort)bf16r(hn);
}

// ---------------- mean pool ALL 5 layers at the end: 320 blocks (g,layer) ----------------

__global__ __launch_bounds__(512) void k_pool5(const ushort* __restrict__ Hb,
                                               const int* __restrict__ bstart,
                                               const float* __restrict__ inv,
                                               float* __restrict__ hcat) {
    __shared__ float red[512];
    int l = blockIdx.x >> 6, g = blockIdx.x & 63;
    int lo = bstart[g], hi = bstart[g + 1];
    const ushort* H = Hb + (size_t)l * NN * 64;
    int ch = threadIdx.x & 63, ro = threadIdx.x >> 6;   // 8 row stripes
    float acc = 0.f;
    for (int r = lo + ro; r < hi; r += 8)
        acc += __uint_as_float((uint)H[(size_t)r * 64 + ch] << 16);
    red[threadIdx.x] = acc;
    __syncthreads();
    if (ro < 4) red[threadIdx.x] += red[threadIdx.x + 256];
    __syncthreads();
    if (ro < 2) red[threadIdx.x] += red[threadIdx.x + 128];
    __syncthreads();
    if (ro == 0)
        hcat[g * 320 + l * 64 + ch] = (red[ch] + red[64 + ch]) * inv[g];
}

// ---------------- final MLP: one block per graph ----------------

__global__ __launch_bounds__(256) void k_mlp(const float* __restrict__ hcat,
                                             const float* __restrict__ W1,
                                             const float* __restrict__ b1,
                                             const float* __restrict__ W2,
                                             const float* __restrict__ b2,
                                             float* __restrict__ out) {
    __shared__ float hc[320];
    __shared__ float red[256];
    int g = blockIdx.x, tid = threadIdx.x;
    for (int i = tid; i < 320; i += 256) hc[i] = hcat[g * 320 + i];
    __syncthreads();
    float part = 0.f;
    for (int j = tid; j < 320; j += 256) {
        float t = b1[j];
        for (int k = 0; k < 320; ++k) t = fmaf(hc[k], W1[k * 320 + j], t);
        part = fmaf(fmaxf(t, 0.f), W2[j], part);
    }
    red[tid] = part;
    __syncthreads();
    for (int off = 128; off > 0; off >>= 1) {
        if (tid < off) red[tid] += red[tid + off];
        __syncthreads();
    }
    if (tid == 0) out[g] = red[0] + b2[0];
}

// ---------------- launch ----------------

extern "C" void kernel_launch(void* const* d_in, const int* in_sizes, int n_in,
                              void* d_out, int out_size, void* d_ws, size_t ws_size,
                              hipStream_t stream) {
    const float* x     = (const float*)d_in[0];
    const int*   ei    = (const int*)d_in[1];     // [2,E]: src then dst
    const float* eattr = (const float*)d_in[2];
    const int*   batch = (const int*)d_in[3];
    const float* Wq    = (const float*)d_in[4];
    const float* Wk    = (const float*)d_in[5];
    const float* Wv    = (const float*)d_in[6];
    const float* We    = (const float*)d_in[7];
    const float* Wsk   = (const float*)d_in[8];
    const float* W1    = (const float*)d_in[9];
    const float* b1    = (const float*)d_in[10];
    const float* W2    = (const float*)d_in[11];
    const float* b2    = (const float*)d_in[12];
    float* out = (float*)d_out;

    const int* srcv = ei;
    const int* dstv = ei + NE;

    // workspace carve (float words; all bases 16B-aligned)
    float* ws = (float*)d_ws;
    size_t o = 0;
    uint*   QQp = (uint*)(ws + o); o += (size_t)NN * 64;
    uint*   KVp = (uint*)(ws + o); o += (size_t)NN * 64;
    float*  Sb  = ws + o;          o += (size_t)NN * 64;
    ushort* Hb  = (ushort*)(ws + o); o += (size_t)5 * NN * 64 / 2;   // 5 bf16 layer outputs
    float*  Mw  = ws + o;          o += 5 * 4096;
    ushort* Wf  = (ushort*)(ws + o); o += 5 * 20 * 2 * 64 * 8 / 2;   // frag-packed weights
    float*  inv = ws + o;          o += GG;
    float*  hcat = ws + o;         o += GG * 320;
    int*    bstart = (int*)(ws + o); o += 68;
    // ---- zeroed region start ----
    int*    deg  = (int*)(ws + o); o += NN;
    int*    srcp = (int*)(ws + o); o += CSR_CAP;   // pad slots must be 0 (safe gathers)
    size_t  zwords = (size_t)NN + CSR_CAP;
    // ---- zeroed region end ----
    int*    rank   = (int*)(ws + o); o += NE;
    int*    off    = (int*)(ws + o); o += NN;
    int*    locoff = (int*)(ws + o); o += NN;
    int*    bsum   = (int*)(ws + o); o += 128;
    ushort* aperm  = (ushort*)(ws + o); o += (size_t)CSR_CAP * 8;    // 16 ushorts/slot

    hipMemsetAsync(deg, 0, zwords * 4, stream);

    k_bounds<<<1, 128, 0, stream>>>(batch, bstart, inv);
    k_degrank<<<(NE + 255) / 256, 256, 0, stream>>>(dstv, deg, rank);
    k_scan1<<<SCAN_NB, SCAN_BLK, 0, stream>>>(deg, locoff, bsum);
    k_scan2<<<1, 128, 0, stream>>>(bsum);
    k_scan3<<<(NN + 255) / 256, 256, 0, stream>>>(locoff, bsum, off);
    k_fill<<<(NE + 255) / 256, 256, 0, stream>>>(srcv, dstv, eattr, off, rank, srcp, aperm);
    k_M<<<(5 * 4096 + 255) / 256, 256, 0, stream>>>(Wq, We, Mw);
    k_wfrag<<<50, 256, 0, stream>>>(Wq, Wk, Wv, Wsk, Mw, Wf);

    for (int l = 0; l < 5; ++l) {
        const ushort* Wfl = Wf + (size_t)l * 20 * 2 * 64 * 8;
        if (l == 0)
            k_projm<true><<<NBLK, 256, 0, stream>>>(x, Hb, Wfl, QQp, KVp, Sb);
        else
            k_projm<false><<<NBLK, 256, 0, stream>>>(x, Hb + (size_t)(l - 1) * NN * 64,
                                                     Wfl, QQp, KVp, Sb);
        k_attn<<<(NN + 3) / 4, 256, 0, stream>>>(QQp, KVp, Sb,
                                                 We + l * 1024, aperm,
                                                 srcp, off, deg,
                                                 Hb + (size_t)l * NN * 64);
    }
    k_pool5<<<320, 512, 0, stream>>>(Hb, bstart, inv, hcat);
    k_mlp<<<GG, 256, 0, stream>>>(hcat, W1, b1, W2, b2, out);
}

// Round 8
// 456.389 us; speedup vs baseline: 2.6537x; 1.1311x over previous
//
#include <hip/hip_runtime.h>
#include <math.h>

#define NN 50000
#define NE 800000
#define GG 64
#define SCAN_BLK 512
#define SCAN_NB ((NN + SCAN_BLK - 1) / SCAN_BLK)   // 98
#define CSR_CAP (NE + 4 * NN)                      // 4-aligned-per-node CSR capacity
#define NBLK ((NN + 63) / 64)                      // 782 proj blocks

typedef unsigned int uint;
typedef unsigned short ushort;
typedef __attribute__((ext_vector_type(8))) short short8v;  // 8 bf16 (4 VGPRs)
typedef __attribute__((ext_vector_type(4))) float f32x4;

__device__ __forceinline__ uint bf16r(float x) {   // RNE f32 -> bf16 bits
    uint u = __float_as_uint(x);
    return (u + 0x7fffu + ((u >> 16) & 1u)) >> 16;
}

// sum over each 8-lane group, broadcast to all 8 (pure DPP: xor1, xor2, half-mirror)
__device__ __forceinline__ float red8(float x) {
    float t;
    t = __int_as_float(__builtin_amdgcn_update_dpp(0, __float_as_int(x), 0xB1, 0xF, 0xF, 1));  // quad_perm [1,0,3,2]
    x += t;
    t = __int_as_float(__builtin_amdgcn_update_dpp(0, __float_as_int(x), 0x4E, 0xF, 0xF, 1));  // quad_perm [2,3,0,1]
    x += t;
    t = __int_as_float(__builtin_amdgcn_update_dpp(0, __float_as_int(x), 0x141, 0xF, 0xF, 1)); // row_half_mirror
    x += t;
    return x;
}

// ---------------- graph segment bounds (batch is sorted) ----------------

__global__ void k_bounds(const int* __restrict__ batch, int* __restrict__ bstart,
                         float* __restrict__ inv) {
    __shared__ int sb[65];
    int t = threadIdx.x;
    if (t <= 64) {
        int lo = 0, hi = NN;
        while (lo < hi) { int mid = (lo + hi) >> 1; if (batch[mid] < t) lo = mid + 1; else hi = mid; }
        sb[t] = lo;
        bstart[t] = lo;
    }
    __syncthreads();
    if (t < 64) inv[t] = 1.0f / fmaxf((float)(sb[t + 1] - sb[t]), 1.0f);
}

// ---------------- CSR build ----------------

__global__ __launch_bounds__(256) void k_degrank(const int* __restrict__ dstv,
                                                 int* __restrict__ deg,
                                                 int* __restrict__ rank) {
    int e = blockIdx.x * 256 + threadIdx.x;
    if (e < NE) rank[e] = atomicAdd(&deg[dstv[e]], 1);
}

__global__ __launch_bounds__(SCAN_BLK) void k_scan1(const int* __restrict__ deg,
                                                    int* __restrict__ locoff,
                                                    int* __restrict__ bsum) {
    __shared__ int sh[SCAN_BLK];
    int tid = threadIdx.x;
    int n = blockIdx.x * SCAN_BLK + tid;
    int v = (n < NN) ? ((deg[n] + 3) & ~3) : 0;
    sh[tid] = v;
    __syncthreads();
    for (int off = 1; off < SCAN_BLK; off <<= 1) {
        int t = (tid >= off) ? sh[tid - off] : 0;
        __syncthreads();
        sh[tid] += t;
        __syncthreads();
    }
    if (n < NN) locoff[n] = sh[tid] - v;   // exclusive
    if (tid == SCAN_BLK - 1) bsum[blockIdx.x] = sh[tid];
}

__global__ void k_scan2(int* __restrict__ bsum) {
    __shared__ int sh[128];
    int t = threadIdx.x;
    int v = (t < SCAN_NB) ? bsum[t] : 0;
    sh[t] = v;
    __syncthreads();
    for (int off = 1; off < 128; off <<= 1) {
        int u = (t >= off) ? sh[t - off] : 0;
        __syncthreads();
        sh[t] += u;
        __syncthreads();
    }
    if (t < SCAN_NB) bsum[t] = sh[t] - v;  // exclusive
}

__global__ __launch_bounds__(256) void k_scan3(const int* __restrict__ locoff,
                                               const int* __restrict__ bsum,
                                               int* __restrict__ off) {
    int n = blockIdx.x * 256 + threadIdx.x;
    if (n < NN) off[n] = locoff[n] + bsum[n >> 9];
}

// fill srcp (as BYTE offsets into KVp rows) + CSR-ordered bf16 attrs
__global__ __launch_bounds__(256) void k_fill(const int* __restrict__ srcv,
                                              const int* __restrict__ dstv,
                                              const float* __restrict__ eattr,
                                              const int* __restrict__ off,
                                              const int* __restrict__ rank,
                                              int* __restrict__ srcp,
                                              ushort* __restrict__ aperm) {
    int e = blockIdx.x * 256 + threadIdx.x;
    if (e >= NE) return;
    int d = dstv[e];
    int p = off[d] + rank[e];
    srcp[p] = srcv[e] << 8;                 // 256 B per KVp row
    const float4* ea = reinterpret_cast<const float4*>(eattr + (size_t)e * 16);
    float4 a = ea[0], b = ea[1], c = ea[2], d4 = ea[3];
    uint4 u0, u1;
    u0.x = bf16r(a.x) | (bf16r(a.y) << 16);
    u0.y = bf16r(a.z) | (bf16r(a.w) << 16);
    u0.z = bf16r(b.x) | (bf16r(b.y) << 16);
    u0.w = bf16r(b.z) | (bf16r(b.w) << 16);
    u1.x = bf16r(c.x) | (bf16r(c.y) << 16);
    u1.y = bf16r(c.z) | (bf16r(c.w) << 16);
    u1.z = bf16r(d4.x) | (bf16r(d4.y) << 16);
    u1.w = bf16r(d4.z) | (bf16r(d4.w) << 16);
    uint4* ap = reinterpret_cast<uint4*>(aperm + (size_t)p * 16);
    ap[0] = u0;
    ap[1] = u1;
}

// M[l][i][c] = sum_dd Wq[l][i][h*16+dd] * We[l][j][h*16+dd],  c = h*16+j
__global__ __launch_bounds__(256) void k_M(const float* __restrict__ Wq,
                                           const float* __restrict__ We,
                                           float* __restrict__ M) {
    int t = blockIdx.x * 256 + threadIdx.x;
    if (t >= 5 * 64 * 64) return;
    int l = t >> 12, i = (t >> 6) & 63, c = t & 63;
    int hh = c >> 4, j = c & 15;
    const float* wq = Wq + l * 4096 + i * 64 + hh * 16;
    const float* we = We + l * 1024 + j * 64 + hh * 16;
    float acc = 0.f;
#pragma unroll
    for (int dd = 0; dd < 16; ++dd) acc += wq[dd] * we[dd];
    M[t] = acc;
}

// ---------------- pack combined weight matrix into MFMA B-fragment order ----------------
// Wall[64k][320c] = [Wq|Wk|Wv|Wsk|M] per layer; frag (nt,s): lane l holds
// B[k = s*32 + 8*(l>>4) + j][c = nt*16 + (l&15)], j=0..7 -> Wf[l][nt][s][l][j] bf16
// Q and M columns pre-scaled by C2 = 0.25*log2(e) (softmax scale folded in).

__global__ __launch_bounds__(256) void k_wfrag(const float* __restrict__ Wq,
                                               const float* __restrict__ Wk,
                                               const float* __restrict__ Wv,
                                               const float* __restrict__ Wsk,
                                               const float* __restrict__ Mw,
                                               ushort* __restrict__ Wf) {
    int t = blockIdx.x * 256 + threadIdx.x;
    if (t >= 5 * 20 * 2 * 64) return;
    int l = t / (20 * 2 * 64);
    int rem = t % (20 * 2 * 64);
    int nt = rem >> 7, s = (rem >> 6) & 1, lane = rem & 63;
    int c = nt * 16 + (lane & 15);
    int k0 = s * 32 + 8 * (lane >> 4);
    int msel = c >> 6, cc = c & 63;
    const float* W = (msel == 0) ? Wq + l * 4096 :
                     (msel == 1) ? Wk + l * 4096 :
                     (msel == 2) ? Wv + l * 4096 :
                     (msel == 3) ? Wsk + l * 4096 : Mw + l * 4096;
    const float C2 = 0.36067376022224085f;
    float sc = (msel == 0 || msel == 4) ? C2 : 1.0f;
    ushort o[8];
#pragma unroll
    for (int j = 0; j < 8; ++j) o[j] = (ushort)bf16r(W[(k0 + j) * 64 + cc] * sc);
    uint4* dst = reinterpret_cast<uint4*>(Wf + (size_t)t * 8);
    uint4 u;
    u.x = (uint)o[0] | ((uint)o[1] << 16);
    u.y = (uint)o[2] | ((uint)o[3] << 16);
    u.z = (uint)o[4] | ((uint)o[5] << 16);
    u.w = (uint)o[6] | ((uint)o[7] << 16);
    dst[0] = u;
}

// ---------------- MFMA projection: [64 nodes] x [64] @ [64 x 320], LDS-free ----------------

template<bool L0>
__global__ __launch_bounds__(256) void k_projm(const float* __restrict__ x,
                                               const ushort* __restrict__ Hin,
                                               const ushort* __restrict__ Wfl,
                                               uint* __restrict__ QQp,
                                               uint* __restrict__ KVp,
                                               float* __restrict__ Sb) {
    int tid = threadIdx.x, lane = tid & 63, wv = tid >> 6;
    int n0 = blockIdx.x * 64;
    int arow = lane & 15, agrp = lane >> 4;

    short8v A[4][2];
#pragma unroll
    for (int mt = 0; mt < 4; ++mt) {
        int node = n0 + mt * 16 + arow;
        if (node >= NN) node = NN - 1;        // clamped load; stores guarded below
#pragma unroll
        for (int s = 0; s < 2; ++s) {
            int k0 = s * 32 + agrp * 8;
            if (L0) {
                const float* hp = x + (size_t)node * 64 + k0;
                float4 u = *reinterpret_cast<const float4*>(hp);
                float4 v = *reinterpret_cast<const float4*>(hp + 4);
                short8v a;
                a[0] = (short)bf16r(u.x); a[1] = (short)bf16r(u.y);
                a[2] = (short)bf16r(u.z); a[3] = (short)bf16r(u.w);
                a[4] = (short)bf16r(v.x); a[5] = (short)bf16r(v.y);
                a[6] = (short)bf16r(v.z); a[7] = (short)bf16r(v.w);
                A[mt][s] = a;
            } else {
                A[mt][s] = *reinterpret_cast<const short8v*>(Hin + (size_t)node * 64 + k0);
            }
        }
    }

    int ch = wv * 16 + arow;
    int rb = agrp * 4;
    f32x4 qh[4], kh[4];
    const f32x4 z = {0.f, 0.f, 0.f, 0.f};

#pragma unroll
    for (int ni = 0; ni < 5; ++ni) {
        int ntl = wv + 4 * ni;   // col-tile: ni selects {Q,K,V,Sk,QW}, wv the 16-ch slice
        f32x4 acc[4] = {z, z, z, z};
#pragma unroll
        for (int s = 0; s < 2; ++s) {
            short8v B = *reinterpret_cast<const short8v*>(
                Wfl + (((size_t)ntl * 2 + s) * 64 + lane) * 8);
#pragma unroll
            for (int mt = 0; mt < 4; ++mt)
                acc[mt] = __builtin_amdgcn_mfma_f32_16x16x32_bf16(A[mt][s], B, acc[mt], 0, 0, 0);
        }
        if (ni == 0) {
#pragma unroll
            for (int mt = 0; mt < 4; ++mt) qh[mt] = acc[mt];
        } else if (ni == 1) {
#pragma unroll
            for (int mt = 0; mt < 4; ++mt) kh[mt] = acc[mt];
        } else if (ni == 2) {            // V ready: pack K|V
#pragma unroll
            for (int mt = 0; mt < 4; ++mt)
#pragma unroll
                for (int r = 0; r < 4; ++r) {
                    int node = n0 + mt * 16 + rb + r;
                    if (node < NN)
                        KVp[(size_t)node * 64 + ch] = (bf16r(kh[mt][r]) << 16) | bf16r(acc[mt][r]);
                }
        } else if (ni == 3) {            // skip projection, f32
#pragma unroll
            for (int mt = 0; mt < 4; ++mt)
#pragma unroll
                for (int r = 0; r < 4; ++r) {
                    int node = n0 + mt * 16 + rb + r;
                    if (node < NN) Sb[(size_t)node * 64 + ch] = acc[mt][r];
                }
        } else {                          // QW ready: pack Q|QW
#pragma unroll
            for (int mt = 0; mt < 4; ++mt)
#pragma unroll
                for (int r = 0; r < 4; ++r) {
                    int node = n0 + mt * 16 + rb + r;
                    if (node < NN)
                        QQp[(size_t)node * 64 + ch] = (bf16r(qh[mt][r]) << 16) | bf16r(acc[mt][r]);
                }
        }
    }
}

// ---------------- attention: 2 edges/wave x 32 lanes x 2 channels/lane ----------------
// lane = eh*32 + pc: eh = edge half, pc = channel pair (head hd = pc>>3).
// 8-lane DPP reduce, no max-tracking (logits bounded: |l| << exp2 range),
// scale pre-folded into weights; halves merged once per node.

__global__ __launch_bounds__(256) void k_attn(const uint* __restrict__ QQp,
                                              const uint* __restrict__ KVp,
                                              const float* __restrict__ Sb,
                                              const float* __restrict__ Wel,
                                              const uint* __restrict__ aperm32,
                                              const int* __restrict__ srcp,
                                              const int* __restrict__ offp,
                                              const int* __restrict__ cnt,
                                              ushort* __restrict__ Hout) {
    __shared__ float we[16 * 64];   // 4 KB, f32 [j][c]
    int tid = threadIdx.x;
    for (int i = tid; i < 1024; i += 256) we[i] = Wel[i];
    __syncthreads();

    int lane = tid & 63;
    int n = blockIdx.x * 4 + (tid >> 6);
    if (n >= NN) return;

    int pc = lane & 31;      // channel pair -> channels 2pc, 2pc+1
    int eh = lane >> 5;      // edge half
    int hd = pc >> 3;        // head

    uint2 qq = *reinterpret_cast<const uint2*>(QQp + n * 64 + 2 * pc);
    float qf0  = __uint_as_float(qq.x & 0xffff0000u);
    float qwf0 = __uint_as_float(qq.x << 16);
    float qf1  = __uint_as_float(qq.y & 0xffff0000u);
    float qwf1 = __uint_as_float(qq.y << 16);

    int dg = cnt[n], pos0 = offp[n];
    int npass = (dg + 1) >> 1;
    int nsb = (npass + 1) >> 1;          // superbatch = 4 edges = 2 passes

    const char* kvb = (const char*)KVp + pc * 8;
    const uint* apb = aperm32 + (size_t)pos0 * 8 + (pc & 7) + eh * 8;

    float s = 0.f, av0 = 0.f, av1 = 0.f, aa0 = 0.f, aa1 = 0.f;

    auto ldidx = [&](int j, int4& s4) {
        s4 = (j < nsb) ? *reinterpret_cast<const int4*>(srcp + pos0 + j * 4)
                       : make_int4(0, 0, 0, 0);
    };
    auto issueSB = [&](int j, const int4& s4, uint2 (&kv)[2], uint (&au)[2]) {
        int sn0 = eh ? s4.y : s4.x;          // pass 0: slots j*4 + {0,1}
        int sn1 = eh ? s4.w : s4.z;          // pass 1: slots j*4 + {2,3}
        kv[0] = *reinterpret_cast<const uint2*>(kvb + sn0);
        kv[1] = *reinterpret_cast<const uint2*>(kvb + sn1);
        const uint* a = apb + (size_t)j * 32;
        au[0] = a[0];
        au[1] = a[16];
    };
    auto computeSB = [&](int j, const uint2 (&kv)[2], const uint (&au)[2]) {
#pragma unroll
        for (int p = 0; p < 2; ++p) {
            float kf0 = __uint_as_float(kv[p].x & 0xffff0000u);
            float vf0 = __uint_as_float(kv[p].x << 16);
            float kf1 = __uint_as_float(kv[p].y & 0xffff0000u);
            float vf1 = __uint_as_float(kv[p].y << 16);
            float af0 = __uint_as_float(au[p] << 16);
            float af1 = __uint_as_float(au[p] & 0xffff0000u);
            float d = qf0 * kf0;
            d = fmaf(qf1, kf1, d);
            d = fmaf(qwf0, af0, d);
            d = fmaf(qwf1, af1, d);
            d = red8(d);
            int ei = j * 4 + p * 2 + eh;
            float l = (ei < dg) ? d : -1e30f;
            float a = __builtin_amdgcn_exp2f(l);
            s += a;
            av0 = fmaf(a, vf0, av0);
            av1 = fmaf(a, vf1, av1);
            aa0 = fmaf(a, af0, aa0);
            aa1 = fmaf(a, af1, aa1);
        }
    };

    int4 s4a, s4b;
    uint2 kvA[2], kvB[2];
    uint auA[2], auB[2];

    ldidx(0, s4a);
    issueSB(0, s4a, kvA, auA);
    ldidx(1, s4b);

    int sb = 0;
    while (sb + 1 < nsb) {
        issueSB(sb + 1, s4b, kvB, auB);
        ldidx(sb + 2, s4a);
        computeSB(sb, kvA, auA);
        if (sb + 2 < nsb) {
            issueSB(sb + 2, s4a, kvA, auA);
            ldidx(sb + 3, s4b);
        }
        computeSB(sb + 1, kvB, auB);
        sb += 2;
    }
    if (sb < nsb) computeSB(sb, kvA, auA);

    // merge the two edge-halves
    s   += __shfl_xor(s, 32);
    av0 += __shfl_xor(av0, 32);
    av1 += __shfl_xor(av1, 32);
    aa0 += __shfl_xor(aa0, 32);
    aa1 += __shfl_xor(aa1, 32);

    float rden = 1.0f / (s + 1e-16f);
    float e0 = 0.f, e1 = 0.f;
#pragma unroll
    for (int t = 0; t < 8; ++t) {
        float ae = __shfl(aa0, hd * 8 + t, 32);   // attr channel 2t
        float ao = __shfl(aa1, hd * 8 + t, 32);   // attr channel 2t+1
        float2 wE = *reinterpret_cast<const float2*>(&we[(2 * t) * 64 + 2 * pc]);
        float2 wO = *reinterpret_cast<const float2*>(&we[(2 * t + 1) * 64 + 2 * pc]);
        e0 = fmaf(ae, wE.x, fmaf(ao, wO.x, e0));
        e1 = fmaf(ae, wE.y, fmaf(ao, wO.y, e1));
    }
    float2 sb2 = *reinterpret_cast<const float2*>(Sb + n * 64 + 2 * pc);
    float hn0 = fmaxf(fmaf(av0 + e0, rden, sb2.x), 0.f);
    float hn1 = fmaxf(fmaf(av1 + e1, rden, sb2.y), 0.f);
    if (lane < 32) {
        uint hw = bf16r(hn0) | (bf16r(hn1) << 16);
        reinterpret_cast<uint*>(Hout)[(size_t)n * 32 + pc] = hw;
    }
}

// ---------------- mean pool ALL 5 layers at the end: 320 blocks (g,layer) ----------------

__global__ __launch_bounds__(512) void k_pool5(const ushort* __restrict__ Hb,
                                               const int* __restrict__ bstart,
                                               const float* __restrict__ inv,
                                               float* __restrict__ hcat) {
    __shared__ float red[512];
    int l = blockIdx.x >> 6, g = blockIdx.x & 63;
    int lo = bstart[g], hi = bstart[g + 1];
    const ushort* H = Hb + (size_t)l * NN * 64;
    int ch = threadIdx.x & 63, ro = threadIdx.x >> 6;   // 8 row stripes
    float acc = 0.f;
    for (int r = lo + ro; r < hi; r += 8)
        acc += __uint_as_float((uint)H[(size_t)r * 64 + ch] << 16);
    red[threadIdx.x] = acc;
    __syncthreads();
    if (ro < 4) red[threadIdx.x] += red[threadIdx.x + 256];
    __syncthreads();
    if (ro < 2) red[threadIdx.x] += red[threadIdx.x + 128];
    __syncthreads();
    if (ro == 0)
        hcat[g * 320 + l * 64 + ch] = (red[ch] + red[64 + ch]) * inv[g];
}

// ---------------- final MLP: one block per graph ----------------

__global__ __launch_bounds__(256) void k_mlp(const float* __restrict__ hcat,
                                             const float* __restrict__ W1,
                                             const float* __restrict__ b1,
                                             const float* __restrict__ W2,
                                             const float* __restrict__ b2,
                                             float* __restrict__ out) {
    __shared__ float hc[320];
    __shared__ float red[256];
    int g = blockIdx.x, tid = threadIdx.x;
    for (int i = tid; i < 320; i += 256) hc[i] = hcat[g * 320 + i];
    __syncthreads();
    float part = 0.f;
    for (int j = tid; j < 320; j += 256) {
        float t = b1[j];
        for (int k = 0; k < 320; ++k) t = fmaf(hc[k], W1[k * 320 + j], t);
        part = fmaf(fmaxf(t, 0.f), W2[j], part);
    }
    red[tid] = part;
    __syncthreads();
    for (int off = 128; off > 0; off >>= 1) {
        if (tid < off) red[tid] += red[tid + off];
        __syncthreads();
    }
    if (tid == 0) out[g] = red[0] + b2[0];
}

// ---------------- launch ----------------

extern "C" void kernel_launch(void* const* d_in, const int* in_sizes, int n_in,
                              void* d_out, int out_size, void* d_ws, size_t ws_size,
                              hipStream_t stream) {
    const float* x     = (const float*)d_in[0];
    const int*   ei    = (const int*)d_in[1];     // [2,E]: src then dst
    const float* eattr = (const float*)d_in[2];
    const int*   batch = (const int*)d_in[3];
    const float* Wq    = (const float*)d_in[4];
    const float* Wk    = (const float*)d_in[5];
    const float* Wv    = (const float*)d_in[6];
    const float* We    = (const float*)d_in[7];
    const float* Wsk   = (const float*)d_in[8];
    const float* W1    = (const float*)d_in[9];
    const float* b1    = (const float*)d_in[10];
    const float* W2    = (const float*)d_in[11];
    const float* b2    = (const float*)d_in[12];
    float* out = (float*)d_out;

    const int* srcv = ei;
    const int* dstv = ei + NE;

    // workspace carve (float words; all bases 16B-aligned)
    float* ws = (float*)d_ws;
    size_t o = 0;
    uint*   QQp = (uint*)(ws + o); o += (size_t)NN * 64;
    uint*   KVp = (uint*)(ws + o); o += (size_t)NN * 64;
    float*  Sb  = ws + o;          o += (size_t)NN * 64;
    ushort* Hb  = (ushort*)(ws + o); o += (size_t)5 * NN * 64 / 2;   // 5 bf16 layer outputs
    float*  Mw  = ws + o;          o += 5 * 4096;
    ushort* Wf  = (ushort*)(ws + o); o += 5 * 20 * 2 * 64 * 8 / 2;   // frag-packed weights
    float*  inv = ws + o;          o += GG;
    float*  hcat = ws + o;         o += GG * 320;
    int*    bstart = (int*)(ws + o); o += 68;
    // ---- zeroed region start ----
    int*    deg  = (int*)(ws + o); o += NN;
    int*    srcp = (int*)(ws + o); o += CSR_CAP;   // pad slots must be 0 (safe gathers)
    size_t  zwords = (size_t)NN + CSR_CAP;
    // ---- zeroed region end ----
    int*    rank   = (int*)(ws + o); o += NE;
    int*    off    = (int*)(ws + o); o += NN;
    int*    locoff = (int*)(ws + o); o += NN;
    int*    bsum   = (int*)(ws + o); o += 128;
    ushort* aperm  = (ushort*)(ws + o); o += (size_t)CSR_CAP * 8;    // 16 ushorts/slot

    hipMemsetAsync(deg, 0, zwords * 4, stream);

    k_bounds<<<1, 128, 0, stream>>>(batch, bstart, inv);
    k_degrank<<<(NE + 255) / 256, 256, 0, stream>>>(dstv, deg, rank);
    k_scan1<<<SCAN_NB, SCAN_BLK, 0, stream>>>(deg, locoff, bsum);
    k_scan2<<<1, 128, 0, stream>>>(bsum);
    k_scan3<<<(NN + 255) / 256, 256, 0, stream>>>(locoff, bsum, off);
    k_fill<<<(NE + 255) / 256, 256, 0, stream>>>(srcv, dstv, eattr, off, rank, srcp, aperm);
    k_M<<<(5 * 4096 + 255) / 256, 256, 0, stream>>>(Wq, We, Mw);
    k_wfrag<<<50, 256, 0, stream>>>(Wq, Wk, Wv, Wsk, Mw, Wf);

    for (int l = 0; l < 5; ++l) {
        const ushort* Wfl = Wf + (size_t)l * 20 * 2 * 64 * 8;
        if (l == 0)
            k_projm<true><<<NBLK, 256, 0, stream>>>(x, Hb, Wfl, QQp, KVp, Sb);
        else
            k_projm<false><<<NBLK, 256, 0, stream>>>(x, Hb + (size_t)(l - 1) * NN * 64,
                                                     Wfl, QQp, KVp, Sb);
        k_attn<<<(NN + 3) / 4, 256, 0, stream>>>(QQp, KVp, Sb,
                                                 We + l * 1024,
                                                 (const uint*)aperm,
                                                 srcp, off, deg,
                                                 Hb + (size_t)l * NN * 64);
    }
    k_pool5<<<320, 512, 0, stream>>>(Hb, bstart, inv, hcat);
    k_mlp<<<GG, 256, 0, stream>>>(hcat, W1, b1, W2, b2, out);
}